// Round 1
// baseline (3324.753 us; speedup 1.0000x reference)
//
#include <hip/hip_runtime.h>

// RelationAggregator: out = x@W_self^T + b + sum_r segment_sum(vals_r * x[src_r]) @ W_r^T
// Restructured as: Y = x @ [W_rels]^T (dense GEMM), then edge scatter of Y rows into out.

__global__ __launch_bounds__(256, 4)
void gemm_kernel(const float* __restrict__ x, const float* __restrict__ Wself,
                 const float* __restrict__ Wrels, const float* __restrict__ bias,
                 float* __restrict__ out, float* __restrict__ Y, int N, int R) {
  // 64x64 output tile, K=128 in two 64-phases. 256 threads, 4x4 per thread.
  __shared__ float xs[64][68];   // pad 68: rows start 4*row banks apart, float4-aligned (272B)
  __shared__ float ws[64][68];
  const int m0 = blockIdx.x * 64;
  const int nt = blockIdx.y;                // 0..(2+2R-1): 0,1 = self; 2.. = relations
  const float* Wp = (nt < 2) ? (Wself + nt * 64 * 128)
                             : (Wrels + (size_t)(nt - 2) * 64 * 128);
  const int t  = threadIdx.x;
  const int tm = t >> 4;    // 0..15
  const int tn = t & 15;    // 0..15
  float acc[4][4] = {};

  for (int ph = 0; ph < 2; ++ph) {
    __syncthreads();   // protect previous phase's tiles before overwrite
    #pragma unroll
    for (int i = 0; i < 4; ++i) {
      int L   = t + i * 256;      // 0..1023
      int row = L >> 4;           // 0..63
      int c4  = L & 15;           // 0..15 (float4 col)
      int gm  = m0 + row;
      float4 xv = make_float4(0.f, 0.f, 0.f, 0.f);
      if (gm < N) xv = ((const float4*)(x + (size_t)gm * 128 + ph * 64))[c4];
      *((float4*)&xs[row][c4 * 4]) = xv;
      float4 wv = ((const float4*)(Wp + (size_t)row * 128 + ph * 64))[c4];
      *((float4*)&ws[row][c4 * 4]) = wv;
    }
    __syncthreads();
    #pragma unroll
    for (int kk = 0; kk < 16; ++kk) {
      float4 a[4], b[4];
      #pragma unroll
      for (int i = 0; i < 4; ++i) a[i] = *(const float4*)&xs[i * 16 + tm][kk * 4];
      #pragma unroll
      for (int j = 0; j < 4; ++j) b[j] = *(const float4*)&ws[j * 16 + tn][kk * 4];
      #pragma unroll
      for (int i = 0; i < 4; ++i)
        #pragma unroll
        for (int j = 0; j < 4; ++j) {
          acc[i][j] += a[i].x * b[j].x;
          acc[i][j] += a[i].y * b[j].y;
          acc[i][j] += a[i].z * b[j].z;
          acc[i][j] += a[i].w * b[j].w;
        }
    }
  }

  const int YS = R * 128;  // Y row stride in floats
  #pragma unroll
  for (int i = 0; i < 4; ++i) {
    int gm = m0 + i * 16 + tm;
    if (gm >= N) continue;
    #pragma unroll
    for (int j = 0; j < 4; ++j) {
      int col = j * 16 + tn;
      float v = acc[i][j];
      if (nt < 2) {
        int oc = nt * 64 + col;
        out[(size_t)gm * 128 + oc] = v + bias[oc];
      } else {
        int q = nt - 2;
        Y[(size_t)gm * YS + q * 64 + col] = v;
      }
    }
  }
}

// One 32-lane group per edge: gather 128 floats of Y[src] (as 32 float4),
// scale by val, atomicAdd into out[dst].
__global__ __launch_bounds__(256)
void scatter_kernel(const float* __restrict__ Y, const int* __restrict__ src,
                    const int* __restrict__ dst, const float* __restrict__ vals,
                    float* __restrict__ out, long long total_slots, int E, int YS4) {
  long long tid  = (long long)blockIdx.x * 256 + threadIdx.x;
  long long slot = tid >> 5;
  int lane = (int)(tid & 31);
  if (slot >= total_slots) return;
  int   r = (int)(slot / E);
  int   s = src[slot];
  int   d = dst[slot];
  float v = vals[slot];
  float4 y = ((const float4*)Y)[(size_t)s * YS4 + r * 32 + lane];
  float* o = out + (size_t)d * 128 + lane * 4;
  atomicAdd(o + 0, v * y.x);
  atomicAdd(o + 1, v * y.y);
  atomicAdd(o + 2, v * y.z);
  atomicAdd(o + 3, v * y.w);
}

extern "C" void kernel_launch(void* const* d_in, const int* in_sizes, int n_in,
                              void* d_out, int out_size, void* d_ws, size_t ws_size,
                              hipStream_t stream) {
  const float* x     = (const float*)d_in[0];
  const int*   src   = (const int*)d_in[1];
  const int*   dst   = (const int*)d_in[2];
  const float* vals  = (const float*)d_in[3];
  const float* Wself = (const float*)d_in[4];
  const float* bias  = (const float*)d_in[5];
  const float* Wrels = (const float*)d_in[6];
  float*       out   = (float*)d_out;

  const int N = in_sizes[0] / 128;            // D_IN = 128
  const int R = in_sizes[6] / (128 * 128);    // W_rels = [R,128,128]
  const int E = in_sizes[1] / R;              // src = [R,E]

  float* Y = (float*)d_ws;                    // [N, R*128] fp32

  dim3 g1((N + 63) / 64, 2 + 2 * R);
  gemm_kernel<<<g1, 256, 0, stream>>>(x, Wself, Wrels, bias, out, Y, N, R);

  long long slots   = (long long)R * E;
  long long threads = slots * 32;
  int blocks = (int)((threads + 255) / 256);
  scatter_kernel<<<blocks, 256, 0, stream>>>(Y, src, dst, vals, out, slots, E, R * 32);
}

// Round 3
// 1082.669 us; speedup vs baseline: 3.0709x; 3.0709x over previous
//
#include <hip/hip_runtime.h>

// out = x@W_self^T + b + sum_r segment_sum(vals_r * x[src_r]) @ W_r^T
// Fast path: on-device CSR by dst (int atomics only) -> register aggregation of x
// into Agg[N, R*128] -> one fused fp32 GEMM out = [x|Agg] @ [Wself|Wcat]^T + b.

// ---------------- CSR build ----------------

__global__ void zero_kernel(int* p, int n) {
  int i = blockIdx.x * 256 + threadIdx.x;
  if (i < n) p[i] = 0;
}

__global__ void hist_kernel(const int* __restrict__ dst, int* __restrict__ counts, int total) {
  int i = blockIdx.x * 256 + threadIdx.x;
  if (i < total) atomicAdd(&counts[dst[i]], 1);
}

// exclusive prefix of counts -> cursor. Single block, 1024 threads.
__global__ __launch_bounds__(1024)
void scan_kernel(const int* __restrict__ counts, int* __restrict__ cursor, int N) {
  __shared__ int lds[1024];
  int t = threadIdx.x;
  int C = (N + 1023) >> 10;
  int base = t * C;
  int s = 0;
  for (int j = 0; j < C; ++j) {
    int idx = base + j;
    if (idx < N) s += counts[idx];
  }
  lds[t] = s;
  __syncthreads();
  for (int off = 1; off < 1024; off <<= 1) {
    int v = (t >= off) ? lds[t - off] : 0;
    __syncthreads();
    lds[t] += v;
    __syncthreads();
  }
  int run = lds[t] - s;  // exclusive prefix of this thread's chunk
  for (int j = 0; j < C; ++j) {
    int idx = base + j;
    if (idx < N) { cursor[idx] = run; run += counts[idx]; }
  }
}

// place each edge slot into its dst's CSR segment. After this, cursor[d] == inclusive prefix.
__global__ void fill_kernel(const int* __restrict__ dst, int* __restrict__ cursor,
                            unsigned* __restrict__ perm, int total, int E) {
  int i = blockIdx.x * 256 + threadIdx.x;
  if (i >= total) return;
  int d = dst[i];
  int p = atomicAdd(&cursor[d], 1);
  int r = i / E;
  int le = i - r * E;              // < 2^20
  perm[p] = ((unsigned)r << 20) | (unsigned)le;
}

// ---------------- register aggregation (no fp32 atomics) ----------------
// One 64-lane wave per dst node; float2 per lane per relation (R=3).
__global__ __launch_bounds__(256)
void aggregate_kernel(const float* __restrict__ x, const int* __restrict__ src,
                      const float* __restrict__ vals, const int* __restrict__ cursor,
                      const unsigned* __restrict__ perm, float* __restrict__ Agg,
                      int N, int E) {
  int wid = blockIdx.x * 4 + (threadIdx.x >> 6);
  if (wid >= N) return;
  int lane = threadIdx.x & 63;
  int pstart = (wid == 0) ? 0 : cursor[wid - 1];
  int pend   = cursor[wid];
  float2 a0 = {0.f, 0.f}, a1 = {0.f, 0.f}, a2 = {0.f, 0.f};
  for (int p = pstart; p < pend; ++p) {
    unsigned w = perm[p];
    int r  = (int)(w >> 20);
    int le = (int)(w & 0xFFFFFu);
    int idx = r * E + le;
    int   s = src[idx];
    float v = vals[idx];
    float2 xv = *(const float2*)(x + (size_t)s * 128 + lane * 2);
    if (r == 0)      { a0.x += v * xv.x; a0.y += v * xv.y; }
    else if (r == 1) { a1.x += v * xv.x; a1.y += v * xv.y; }
    else             { a2.x += v * xv.x; a2.y += v * xv.y; }
  }
  float* ag = Agg + (size_t)wid * 384 + lane * 2;
  *(float2*)(ag)       = a0;
  *(float2*)(ag + 128) = a1;
  *(float2*)(ag + 256) = a2;
}

// ---------------- fused GEMM: out = [x|Agg] @ [Wself|Wcat]^T + b ----------------
// Tile 128x64, 256 threads, 8x4 per thread. K = 128 + R*128 in 32-wide phases.
__global__ __launch_bounds__(256)
void gemm_fused(const float* __restrict__ x, const float* __restrict__ Agg,
                const float* __restrict__ Wself, const float* __restrict__ Wrels,
                const float* __restrict__ bias, float* __restrict__ out, int N, int R) {
  __shared__ float xs[128][36];
  __shared__ float ws[64][36];
  const int m0 = blockIdx.x * 128;
  const int n0 = blockIdx.y * 64;
  const int t  = threadIdx.x;
  const int tm = t >> 4;   // 0..15
  const int tn = t & 15;   // 0..15
  const int AggLD = R * 128;
  float acc[8][4] = {};

  const int nph = 4 + 4 * R;
  for (int ph = 0; ph < nph; ++ph) {
    const float* Ap; int lda;
    const float* Bp;
    if (ph < 4) {
      Ap = x + (size_t)m0 * 128 + ph * 32;  lda = 128;
      Bp = Wself + (size_t)n0 * 128 + ph * 32;
    } else {
      int q = ph - 4;
      Ap = Agg + (size_t)m0 * AggLD + q * 32;  lda = AggLD;
      Bp = Wrels + (size_t)(q >> 2) * 16384 + (size_t)n0 * 128 + (q & 3) * 32;
    }
    __syncthreads();
    #pragma unroll
    for (int i = 0; i < 4; ++i) {          // xs: 128 rows x 8 float4
      int L = t + i * 256;                  // 0..1023
      int row = L >> 3, c4 = L & 7;
      float4 v = make_float4(0.f, 0.f, 0.f, 0.f);
      if (m0 + row < N) v = *(const float4*)(Ap + (size_t)row * lda + c4 * 4);
      *(float4*)&xs[row][c4 * 4] = v;
    }
    #pragma unroll
    for (int i = 0; i < 2; ++i) {          // ws: 64 rows x 8 float4
      int L = t + i * 256;                  // 0..511
      int row = L >> 3, c4 = L & 7;
      *(float4*)&ws[row][c4 * 4] = *(const float4*)(Bp + (size_t)row * 128 + c4 * 4);
    }
    __syncthreads();
    #pragma unroll
    for (int kk = 0; kk < 8; ++kk) {
      float4 a[8], b[4];
      #pragma unroll
      for (int i = 0; i < 8; ++i) a[i] = *(const float4*)&xs[i * 16 + tm][kk * 4];
      #pragma unroll
      for (int j = 0; j < 4; ++j) b[j] = *(const float4*)&ws[j * 16 + tn][kk * 4];
      #pragma unroll
      for (int i = 0; i < 8; ++i)
        #pragma unroll
        for (int j = 0; j < 4; ++j) {
          acc[i][j] += a[i].x * b[j].x;
          acc[i][j] += a[i].y * b[j].y;
          acc[i][j] += a[i].z * b[j].z;
          acc[i][j] += a[i].w * b[j].w;
        }
    }
  }

  #pragma unroll
  for (int i = 0; i < 8; ++i) {
    int gm = m0 + i * 16 + tm;
    if (gm >= N) continue;
    #pragma unroll
    for (int j = 0; j < 4; ++j) {
      int col = n0 + j * 16 + tn;
      out[(size_t)gm * 128 + col] = acc[i][j] + bias[col];
    }
  }
}

// ---------------- fallback path (round-1, proven) ----------------

__global__ __launch_bounds__(256, 4)
void gemm_kernel(const float* __restrict__ x, const float* __restrict__ Wself,
                 const float* __restrict__ Wrels, const float* __restrict__ bias,
                 float* __restrict__ out, float* __restrict__ Y, int N, int R) {
  __shared__ float xs[64][68];
  __shared__ float ws[64][68];
  const int m0 = blockIdx.x * 64;
  const int nt = blockIdx.y;
  const float* Wp = (nt < 2) ? (Wself + nt * 64 * 128)
                             : (Wrels + (size_t)(nt - 2) * 64 * 128);
  const int t  = threadIdx.x;
  const int tm = t >> 4;
  const int tn = t & 15;
  float acc[4][4] = {};
  for (int ph = 0; ph < 2; ++ph) {
    __syncthreads();
    #pragma unroll
    for (int i = 0; i < 4; ++i) {
      int L = t + i * 256;
      int row = L >> 4;
      int c4 = L & 15;
      int gm = m0 + row;
      float4 xv = make_float4(0.f, 0.f, 0.f, 0.f);
      if (gm < N) xv = ((const float4*)(x + (size_t)gm * 128 + ph * 64))[c4];
      *((float4*)&xs[row][c4 * 4]) = xv;
      float4 wv = ((const float4*)(Wp + (size_t)row * 128 + ph * 64))[c4];
      *((float4*)&ws[row][c4 * 4]) = wv;
    }
    __syncthreads();
    #pragma unroll
    for (int kk = 0; kk < 16; ++kk) {
      float4 a[4], b[4];
      #pragma unroll
      for (int i = 0; i < 4; ++i) a[i] = *(const float4*)&xs[i * 16 + tm][kk * 4];
      #pragma unroll
      for (int j = 0; j < 4; ++j) b[j] = *(const float4*)&ws[j * 16 + tn][kk * 4];
      #pragma unroll
      for (int i = 0; i < 4; ++i)
        #pragma unroll
        for (int j = 0; j < 4; ++j) {
          acc[i][j] += a[i].x * b[j].x;
          acc[i][j] += a[i].y * b[j].y;
          acc[i][j] += a[i].z * b[j].z;
          acc[i][j] += a[i].w * b[j].w;
        }
    }
  }
  const int YS = R * 128;
  #pragma unroll
  for (int i = 0; i < 4; ++i) {
    int gm = m0 + i * 16 + tm;
    if (gm >= N) continue;
    #pragma unroll
    for (int j = 0; j < 4; ++j) {
      int col = j * 16 + tn;
      float v = acc[i][j];
      if (nt < 2) {
        int oc = nt * 64 + col;
        out[(size_t)gm * 128 + oc] = v + bias[oc];
      } else {
        int q = nt - 2;
        Y[(size_t)gm * YS + q * 64 + col] = v;
      }
    }
  }
}

__global__ __launch_bounds__(256)
void scatter_kernel(const float* __restrict__ Y, const int* __restrict__ src,
                    const int* __restrict__ dst, const float* __restrict__ vals,
                    float* __restrict__ out, long long total_slots, int E, int YS4) {
  long long tid = (long long)blockIdx.x * 256 + threadIdx.x;
  long long slot = tid >> 5;
  int lane = (int)(tid & 31);
  if (slot >= total_slots) return;
  int r = (int)(slot / E);
  int s = src[slot];
  int d = dst[slot];
  float v = vals[slot];
  float4 y = ((const float4*)Y)[(size_t)s * YS4 + r * 32 + lane];
  float* o = out + (size_t)d * 128 + lane * 4;
  atomicAdd(o + 0, v * y.x);
  atomicAdd(o + 1, v * y.y);
  atomicAdd(o + 2, v * y.z);
  atomicAdd(o + 3, v * y.w);
}

// ---------------- launch ----------------

extern "C" void kernel_launch(void* const* d_in, const int* in_sizes, int n_in,
                              void* d_out, int out_size, void* d_ws, size_t ws_size,
                              hipStream_t stream) {
  const float* x     = (const float*)d_in[0];
  const int*   src   = (const int*)d_in[1];
  const int*   dst   = (const int*)d_in[2];
  const float* vals  = (const float*)d_in[3];
  const float* Wself = (const float*)d_in[4];
  const float* bias  = (const float*)d_in[5];
  const float* Wrels = (const float*)d_in[6];
  float*       out   = (float*)d_out;

  const int N = in_sizes[0] / 128;
  const int R = in_sizes[6] / (128 * 128);
  const int E = in_sizes[1] / R;
  const int total = R * E;

  // workspace layout (fast path)
  size_t aggBytes  = (size_t)N * R * 128 * sizeof(float);
  size_t cntBytes  = (size_t)N * sizeof(int);
  size_t permBytes = (size_t)total * sizeof(unsigned);
  size_t need = aggBytes + 2 * cntBytes + permBytes + 256;

  if (ws_size >= need && R == 3 && E < (1 << 20)) {
    char* base = (char*)d_ws;
    float*    Agg    = (float*)base;                 base += aggBytes;
    int*      counts = (int*)base;                   base += cntBytes;
    int*      cursor = (int*)base;                   base += cntBytes;
    unsigned* perm   = (unsigned*)base;

    zero_kernel<<<(N + 255) / 256, 256, 0, stream>>>(counts, N);
    hist_kernel<<<(total + 255) / 256, 256, 0, stream>>>(dst, counts, total);
    scan_kernel<<<1, 1024, 0, stream>>>(counts, cursor, N);
    fill_kernel<<<(total + 255) / 256, 256, 0, stream>>>(dst, cursor, perm, total, E);
    aggregate_kernel<<<(N + 3) / 4, 256, 0, stream>>>(x, src, vals, cursor, perm, Agg, N, E);
    dim3 g((N + 127) / 128, 2);
    gemm_fused<<<g, 256, 0, stream>>>(x, Agg, Wself, Wrels, bias, out, N, R);
  } else {
    // fallback: dense Y + atomic scatter (round-1 path)
    float* Y = (float*)d_ws;
    dim3 g1((N + 63) / 64, 2 + 2 * R);
    gemm_kernel<<<g1, 256, 0, stream>>>(x, Wself, Wrels, bias, out, Y, N, R);
    long long slots = (long long)R * E;
    long long threads = slots * 32;
    int blocks = (int)((threads + 255) / 256);
    scatter_kernel<<<blocks, 256, 0, stream>>>(Y, src, dst, vals, out, slots, E, R * 32);
  }
}

// Round 7
// 696.661 us; speedup vs baseline: 4.7724x; 1.5541x over previous
//
#include <hip/hip_runtime.h>

// out = x@W_self^T + b + sum_r segment_sum(vals_r * x[src_r]) @ W_r^T
// Fast path: on-device CSR keyed by (r,dst) (int atomics only) -> sorted edge
// records -> 4-deep-pipelined register aggregation into Agg[N, R*128]
// -> one fused fp32 GEMM out = [x|Agg] @ [Wself|Wcat]^T + b.

// ---------------- CSR build ----------------

__global__ void hist_kernel(const int* __restrict__ dst, int* __restrict__ cursor,
                            int total, int N, int E) {
  int i = blockIdx.x * 256 + threadIdx.x;
  if (i >= total) return;
  int r = i / E;
  atomicAdd(&cursor[r * N + dst[i]], 1);
}

// 3-pass parallel exclusive scan over cursor[KEYS], in place.
// A: per-block (1024 elems) partial sums.
__global__ __launch_bounds__(256)
void scanA_kernel(const int* __restrict__ cursor, int* __restrict__ blockSums, int keys) {
  int t = threadIdx.x;
  int idx = blockIdx.x * 1024 + t * 4;
  int s = 0;
  if (idx < keys) {  // keys % 4 == 0 so vector is fully valid when idx < keys
    int4 v = *(const int4*)(cursor + idx);
    s = v.x + v.y + v.z + v.w;
  }
  __shared__ int lds[256];
  lds[t] = s;
  __syncthreads();
  for (int off = 128; off > 0; off >>= 1) {
    if (t < off) lds[t] += lds[t + off];
    __syncthreads();
  }
  if (t == 0) blockSums[blockIdx.x] = lds[0];
}

// B: single block exclusive-scans blockSums (nb <= 1024) in place.
__global__ __launch_bounds__(1024)
void scanB_kernel(int* __restrict__ blockSums, int nb) {
  __shared__ int lds[1024];
  int t = threadIdx.x;
  int v0 = (t < nb) ? blockSums[t] : 0;
  lds[t] = v0;
  __syncthreads();
  for (int off = 1; off < 1024; off <<= 1) {
    int v = (t >= off) ? lds[t - off] : 0;
    __syncthreads();
    lds[t] += v;
    __syncthreads();
  }
  if (t < nb) blockSums[t] = lds[t] - v0;  // exclusive
}

// C: per-block exclusive scan of its 1024 counts + block offset -> cursor (in place).
__global__ __launch_bounds__(256)
void scanC_kernel(int* __restrict__ cursor, const int* __restrict__ blockSums, int keys) {
  int t = threadIdx.x;
  int idx = blockIdx.x * 1024 + t * 4;
  int4 v = make_int4(0, 0, 0, 0);
  if (idx < keys) v = *(const int4*)(cursor + idx);
  int s = v.x + v.y + v.z + v.w;
  __shared__ int lds[256];
  lds[t] = s;
  __syncthreads();
  for (int off = 1; off < 256; off <<= 1) {
    int u = (t >= off) ? lds[t - off] : 0;
    __syncthreads();
    lds[t] += u;
    __syncthreads();
  }
  int run = blockSums[blockIdx.x] + lds[t] - s;  // exclusive prefix at idx
  if (idx < keys) {
    int4 o;
    o.x = run;              run += v.x;
    o.y = run;              run += v.y;
    o.z = run;              run += v.z;
    o.w = run;
    *(int4*)(cursor + idx) = o;
  }
}

// place each edge into its (r,dst) segment as a sorted (src, val) record.
// After this, cursor[key] == inclusive prefix.
__global__ void fill_kernel(const int* __restrict__ dst, const int* __restrict__ src,
                            const float* __restrict__ vals, int* __restrict__ cursor,
                            int2* __restrict__ edges, int total, int N, int E) {
  int i = blockIdx.x * 256 + threadIdx.x;
  if (i >= total) return;
  int r = i / E;
  int key = r * N + dst[i];
  int p = atomicAdd(&cursor[key], 1);
  edges[p] = make_int2(src[i], __float_as_int(vals[i]));
}

// ---------------- register aggregation (no fp32 atomics) ----------------
// One 64-lane wave per (r,dst) key; float2 per lane; 4 x-row loads in flight.
__global__ __launch_bounds__(256)
void aggregate_kernel(const float* __restrict__ x, const int2* __restrict__ edges,
                      const int* __restrict__ cursor, float* __restrict__ Agg,
                      int N, int R, int keys) {
  int wid = blockIdx.x * 4 + (threadIdx.x >> 6);
  if (wid >= keys) return;
  int lane = threadIdx.x & 63;
  int r = (wid < N) ? 0 : ((wid < 2 * N) ? 1 : 2);
  int d = wid - r * N;
  int pstart = (wid == 0) ? 0 : cursor[wid - 1];
  int pend   = cursor[wid];
  float2 acc = {0.f, 0.f};
  int p = pstart;
  for (; p + 4 <= pend; p += 4) {
    int2 e0 = edges[p + 0];
    int2 e1 = edges[p + 1];
    int2 e2 = edges[p + 2];
    int2 e3 = edges[p + 3];
    float2 x0 = *(const float2*)(x + (size_t)e0.x * 128 + lane * 2);
    float2 x1 = *(const float2*)(x + (size_t)e1.x * 128 + lane * 2);
    float2 x2 = *(const float2*)(x + (size_t)e2.x * 128 + lane * 2);
    float2 x3 = *(const float2*)(x + (size_t)e3.x * 128 + lane * 2);
    float v0 = __int_as_float(e0.y), v1 = __int_as_float(e1.y);
    float v2 = __int_as_float(e2.y), v3 = __int_as_float(e3.y);
    acc.x += v0 * x0.x; acc.y += v0 * x0.y;
    acc.x += v1 * x1.x; acc.y += v1 * x1.y;
    acc.x += v2 * x2.x; acc.y += v2 * x2.y;
    acc.x += v3 * x3.x; acc.y += v3 * x3.y;
  }
  for (; p < pend; ++p) {
    int2 e = edges[p];
    float2 xv = *(const float2*)(x + (size_t)e.x * 128 + lane * 2);
    float v = __int_as_float(e.y);
    acc.x += v * xv.x; acc.y += v * xv.y;
  }
  *(float2*)(Agg + (size_t)d * (R * 128) + r * 128 + lane * 2) = acc;
}

// ---------------- fused GEMM: out = [x|Agg] @ [Wself|Wcat]^T + b ----------------
// Tile 128x64, 256 threads, 8x4 per thread. K = 128 + R*128 in 32-wide phases.
__global__ __launch_bounds__(256)
void gemm_fused(const float* __restrict__ x, const float* __restrict__ Agg,
                const float* __restrict__ Wself, const float* __restrict__ Wrels,
                const float* __restrict__ bias, float* __restrict__ out, int N, int R) {
  __shared__ float xs[128][36];
  __shared__ float ws[64][36];
  const int m0 = blockIdx.x * 128;
  const int n0 = blockIdx.y * 64;
  const int t  = threadIdx.x;
  const int tm = t >> 4;   // 0..15
  const int tn = t & 15;   // 0..15
  const int AggLD = R * 128;
  float acc[8][4] = {};

  const int nph = 4 + 4 * R;
  for (int ph = 0; ph < nph; ++ph) {
    const float* Ap; int lda;
    const float* Bp;
    if (ph < 4) {
      Ap = x + (size_t)m0 * 128 + ph * 32;  lda = 128;
      Bp = Wself + (size_t)n0 * 128 + ph * 32;
    } else {
      int q = ph - 4;
      Ap = Agg + (size_t)m0 * AggLD + q * 32;  lda = AggLD;
      Bp = Wrels + (size_t)(q >> 2) * 16384 + (size_t)n0 * 128 + (q & 3) * 32;
    }
    __syncthreads();
    #pragma unroll
    for (int i = 0; i < 4; ++i) {          // xs: 128 rows x 8 float4
      int L = t + i * 256;                  // 0..1023
      int row = L >> 3, c4 = L & 7;
      float4 v = make_float4(0.f, 0.f, 0.f, 0.f);
      if (m0 + row < N) v = *(const float4*)(Ap + (size_t)row * lda + c4 * 4);
      *(float4*)&xs[row][c4 * 4] = v;
    }
    #pragma unroll
    for (int i = 0; i < 2; ++i) {          // ws: 64 rows x 8 float4
      int L = t + i * 256;                  // 0..511
      int row = L >> 3, c4 = L & 7;
      *(float4*)&ws[row][c4 * 4] = *(const float4*)(Bp + (size_t)row * 128 + c4 * 4);
    }
    __syncthreads();
    #pragma unroll
    for (int kk = 0; kk < 8; ++kk) {
      float4 a[8], b[4];
      #pragma unroll
      for (int i = 0; i < 8; ++i) a[i] = *(const float4*)&xs[i * 16 + tm][kk * 4];
      #pragma unroll
      for (int j = 0; j < 4; ++j) b[j] = *(const float4*)&ws[j * 16 + tn][kk * 4];
      #pragma unroll
      for (int i = 0; i < 8; ++i)
        #pragma unroll
        for (int j = 0; j < 4; ++j) {
          acc[i][j] += a[i].x * b[j].x;
          acc[i][j] += a[i].y * b[j].y;
          acc[i][j] += a[i].z * b[j].z;
          acc[i][j] += a[i].w * b[j].w;
        }
    }
  }

  #pragma unroll
  for (int i = 0; i < 8; ++i) {
    int gm = m0 + i * 16 + tm;
    if (gm >= N) continue;
    #pragma unroll
    for (int j = 0; j < 4; ++j) {
      int col = n0 + j * 16 + tn;
      out[(size_t)gm * 128 + col] = acc[i][j] + bias[col];
    }
  }
}

// ---------------- fallback path (round-1, proven) ----------------

__global__ __launch_bounds__(256, 4)
void gemm_kernel(const float* __restrict__ x, const float* __restrict__ Wself,
                 const float* __restrict__ Wrels, const float* __restrict__ bias,
                 float* __restrict__ out, float* __restrict__ Y, int N, int R) {
  __shared__ float xs[64][68];
  __shared__ float ws[64][68];
  const int m0 = blockIdx.x * 64;
  const int nt = blockIdx.y;
  const float* Wp = (nt < 2) ? (Wself + nt * 64 * 128)
                             : (Wrels + (size_t)(nt - 2) * 64 * 128);
  const int t  = threadIdx.x;
  const int tm = t >> 4;
  const int tn = t & 15;
  float acc[4][4] = {};
  for (int ph = 0; ph < 2; ++ph) {
    __syncthreads();
    #pragma unroll
    for (int i = 0; i < 4; ++i) {
      int L = t + i * 256;
      int row = L >> 4;
      int c4 = L & 15;
      int gm = m0 + row;
      float4 xv = make_float4(0.f, 0.f, 0.f, 0.f);
      if (gm < N) xv = ((const float4*)(x + (size_t)gm * 128 + ph * 64))[c4];
      *((float4*)&xs[row][c4 * 4]) = xv;
      float4 wv = ((const float4*)(Wp + (size_t)row * 128 + ph * 64))[c4];
      *((float4*)&ws[row][c4 * 4]) = wv;
    }
    __syncthreads();
    #pragma unroll
    for (int kk = 0; kk < 16; ++kk) {
      float4 a[4], b[4];
      #pragma unroll
      for (int i = 0; i < 4; ++i) a[i] = *(const float4*)&xs[i * 16 + tm][kk * 4];
      #pragma unroll
      for (int j = 0; j < 4; ++j) b[j] = *(const float4*)&ws[j * 16 + tn][kk * 4];
      #pragma unroll
      for (int i = 0; i < 4; ++i)
        #pragma unroll
        for (int j = 0; j < 4; ++j) {
          acc[i][j] += a[i].x * b[j].x;
          acc[i][j] += a[i].y * b[j].y;
          acc[i][j] += a[i].z * b[j].z;
          acc[i][j] += a[i].w * b[j].w;
        }
    }
  }
  const int YS = R * 128;
  #pragma unroll
  for (int i = 0; i < 4; ++i) {
    int gm = m0 + i * 16 + tm;
    if (gm >= N) continue;
    #pragma unroll
    for (int j = 0; j < 4; ++j) {
      int col = j * 16 + tn;
      float v = acc[i][j];
      if (nt < 2) {
        int oc = nt * 64 + col;
        out[(size_t)gm * 128 + oc] = v + bias[oc];
      } else {
        int q = nt - 2;
        Y[(size_t)gm * YS + q * 64 + col] = v;
      }
    }
  }
}

__global__ __launch_bounds__(256)
void scatter_kernel(const float* __restrict__ Y, const int* __restrict__ src,
                    const int* __restrict__ dst, const float* __restrict__ vals,
                    float* __restrict__ out, long long total_slots, int E, int YS4) {
  long long tid = (long long)blockIdx.x * 256 + threadIdx.x;
  long long slot = tid >> 5;
  int lane = (int)(tid & 31);
  if (slot >= total_slots) return;
  int r = (int)(slot / E);
  int s = src[slot];
  int d = dst[slot];
  float v = vals[slot];
  float4 y = ((const float4*)Y)[(size_t)s * YS4 + r * 32 + lane];
  float* o = out + (size_t)d * 128 + lane * 4;
  atomicAdd(o + 0, v * y.x);
  atomicAdd(o + 1, v * y.y);
  atomicAdd(o + 2, v * y.z);
  atomicAdd(o + 3, v * y.w);
}

// ---------------- launch ----------------

extern "C" void kernel_launch(void* const* d_in, const int* in_sizes, int n_in,
                              void* d_out, int out_size, void* d_ws, size_t ws_size,
                              hipStream_t stream) {
  const float* x     = (const float*)d_in[0];
  const int*   src   = (const int*)d_in[1];
  const int*   dst   = (const int*)d_in[2];
  const float* vals  = (const float*)d_in[3];
  const float* Wself = (const float*)d_in[4];
  const float* bias  = (const float*)d_in[5];
  const float* Wrels = (const float*)d_in[6];
  float*       out   = (float*)d_out;

  const int N = in_sizes[0] / 128;
  const int R = in_sizes[6] / (128 * 128);
  const int E = in_sizes[1] / R;
  const int total = R * E;
  const int keys = R * N;
  const int nb = (keys + 1023) / 1024;   // scan blocks

  // workspace layout (fast path)
  size_t aggBytes  = (size_t)N * R * 128 * sizeof(float);
  size_t curBytes  = ((size_t)keys * sizeof(int) + 255) & ~(size_t)255;
  size_t edgeBytes = (size_t)total * sizeof(int2);
  size_t bsBytes   = ((size_t)nb * sizeof(int) + 255) & ~(size_t)255;
  size_t need = aggBytes + curBytes + edgeBytes + bsBytes + 256;

  if (ws_size >= need && R == 3 && nb <= 1024 && (keys % 4) == 0) {
    char* base = (char*)d_ws;
    float* Agg       = (float*)base;  base += aggBytes;
    int*   cursor    = (int*)base;    base += curBytes;
    int*   blockSums = (int*)base;    base += bsBytes;
    int2*  edges     = (int2*)base;

    hipMemsetAsync(cursor, 0, (size_t)keys * sizeof(int), stream);
    hist_kernel<<<(total + 255) / 256, 256, 0, stream>>>(dst, cursor, total, N, E);
    scanA_kernel<<<nb, 256, 0, stream>>>(cursor, blockSums, keys);
    scanB_kernel<<<1, 1024, 0, stream>>>(blockSums, nb);
    scanC_kernel<<<nb, 256, 0, stream>>>(cursor, blockSums, keys);
    fill_kernel<<<(total + 255) / 256, 256, 0, stream>>>(dst, src, vals, cursor, edges, total, N, E);
    aggregate_kernel<<<(keys + 3) / 4, 256, 0, stream>>>(x, edges, cursor, Agg, N, R, keys);
    dim3 g((N + 127) / 128, 2);
    gemm_fused<<<g, 256, 0, stream>>>(x, Agg, Wself, Wrels, bias, out, N, R);
  } else {
    // fallback: dense Y + atomic scatter (round-1 path)
    float* Y = (float*)d_ws;
    dim3 g1((N + 63) / 64, 2 + 2 * R);
    gemm_kernel<<<g1, 256, 0, stream>>>(x, Wself, Wrels, bias, out, Y, N, R);
    long long slots = (long long)R * E;
    long long threads = slots * 32;
    int blocks = (int)((threads + 255) / 256);
    scatter_kernel<<<blocks, 256, 0, stream>>>(Y, src, dst, vals, out, slots, E, R * 32);
  }
}

// Round 9
// 557.412 us; speedup vs baseline: 5.9646x; 1.2498x over previous
//
#include <hip/hip_runtime.h>

// out = x@W_self^T + b + sum_r segment_sum(vals_r * x[src_r]) @ W_r^T
// Fast path: on-device CSR keyed by (r,dst) -> register aggregation into
// Agg[N, 384] -> bf16-split (hi+lo) MFMA GEMM: out = [x|Agg] @ Wcat^T + b,
// computed as hi*hi + lo*hi + hi*lo in 16x16x32 bf16 MFMA with fp32 accum.

typedef __attribute__((ext_vector_type(8))) short bf16x8;
typedef __attribute__((ext_vector_type(4))) float f32x4;
typedef unsigned short u16;

__device__ inline void split2(float v, u16& h, u16& l) {
  unsigned u = __float_as_uint(v);
  u16 hu = (u16)(u >> 16);                       // truncate-to-bf16 hi
  float r = v - __uint_as_float((unsigned)hu << 16);
  unsigned ur = __float_as_uint(r);
  l = (u16)((ur + 0x7FFF + ((ur >> 16) & 1)) >> 16);  // RNE bf16 lo
  h = hu;
}

// ---------------- CSR build ----------------

__global__ void hist_kernel(const int* __restrict__ dst, int* __restrict__ cursor,
                            int total, int N, int E) {
  int i = blockIdx.x * 256 + threadIdx.x;
  if (i >= total) return;
  int r = i / E;
  atomicAdd(&cursor[r * N + dst[i]], 1);
}

__global__ __launch_bounds__(256)
void scanA_kernel(const int* __restrict__ cursor, int* __restrict__ blockSums, int keys) {
  int t = threadIdx.x;
  int idx = blockIdx.x * 1024 + t * 4;
  int s = 0;
  if (idx < keys) {
    int4 v = *(const int4*)(cursor + idx);
    s = v.x + v.y + v.z + v.w;
  }
  __shared__ int lds[256];
  lds[t] = s;
  __syncthreads();
  for (int off = 128; off > 0; off >>= 1) {
    if (t < off) lds[t] += lds[t + off];
    __syncthreads();
  }
  if (t == 0) blockSums[blockIdx.x] = lds[0];
}

__global__ __launch_bounds__(1024)
void scanB_kernel(int* __restrict__ blockSums, int nb) {
  __shared__ int lds[1024];
  int t = threadIdx.x;
  int v0 = (t < nb) ? blockSums[t] : 0;
  lds[t] = v0;
  __syncthreads();
  for (int off = 1; off < 1024; off <<= 1) {
    int v = (t >= off) ? lds[t - off] : 0;
    __syncthreads();
    lds[t] += v;
    __syncthreads();
  }
  if (t < nb) blockSums[t] = lds[t] - v0;  // exclusive
}

__global__ __launch_bounds__(256)
void scanC_kernel(int* __restrict__ cursor, const int* __restrict__ blockSums, int keys) {
  int t = threadIdx.x;
  int idx = blockIdx.x * 1024 + t * 4;
  int4 v = make_int4(0, 0, 0, 0);
  if (idx < keys) v = *(const int4*)(cursor + idx);
  int s = v.x + v.y + v.z + v.w;
  __shared__ int lds[256];
  lds[t] = s;
  __syncthreads();
  for (int off = 1; off < 256; off <<= 1) {
    int u = (t >= off) ? lds[t - off] : 0;
    __syncthreads();
    lds[t] += u;
    __syncthreads();
  }
  int run = blockSums[blockIdx.x] + lds[t] - s;
  if (idx < keys) {
    int4 o;
    o.x = run;              run += v.x;
    o.y = run;              run += v.y;
    o.z = run;              run += v.z;
    o.w = run;
    *(int4*)(cursor + idx) = o;
  }
}

__global__ void fill_kernel(const int* __restrict__ dst, const int* __restrict__ src,
                            const float* __restrict__ vals, int* __restrict__ cursor,
                            int2* __restrict__ edges, int total, int N, int E) {
  int i = blockIdx.x * 256 + threadIdx.x;
  if (i >= total) return;
  int r = i / E;
  int key = r * N + dst[i];
  int p = atomicAdd(&cursor[key], 1);
  edges[p] = make_int2(src[i], __float_as_int(vals[i]));
}

// ---------------- register aggregation (no fp32 atomics) ----------------

__global__ __launch_bounds__(256)
void aggregate_kernel(const float* __restrict__ x, const int2* __restrict__ edges,
                      const int* __restrict__ cursor, float* __restrict__ Agg,
                      int N, int R, int keys) {
  int wid = blockIdx.x * 4 + (threadIdx.x >> 6);
  if (wid >= keys) return;
  int lane = threadIdx.x & 63;
  int r = (wid < N) ? 0 : ((wid < 2 * N) ? 1 : 2);
  int d = wid - r * N;
  int pstart = (wid == 0) ? 0 : cursor[wid - 1];
  int pend   = cursor[wid];
  float2 acc = {0.f, 0.f};
  int p = pstart;
  for (; p + 4 <= pend; p += 4) {
    int2 e0 = edges[p + 0];
    int2 e1 = edges[p + 1];
    int2 e2 = edges[p + 2];
    int2 e3 = edges[p + 3];
    float2 x0 = *(const float2*)(x + (size_t)e0.x * 128 + lane * 2);
    float2 x1 = *(const float2*)(x + (size_t)e1.x * 128 + lane * 2);
    float2 x2 = *(const float2*)(x + (size_t)e2.x * 128 + lane * 2);
    float2 x3 = *(const float2*)(x + (size_t)e3.x * 128 + lane * 2);
    float v0 = __int_as_float(e0.y), v1 = __int_as_float(e1.y);
    float v2 = __int_as_float(e2.y), v3 = __int_as_float(e3.y);
    acc.x += v0 * x0.x; acc.y += v0 * x0.y;
    acc.x += v1 * x1.x; acc.y += v1 * x1.y;
    acc.x += v2 * x2.x; acc.y += v2 * x2.y;
    acc.x += v3 * x3.x; acc.y += v3 * x3.y;
  }
  for (; p < pend; ++p) {
    int2 e = edges[p];
    float2 xv = *(const float2*)(x + (size_t)e.x * 128 + lane * 2);
    float v = __int_as_float(e.y);
    acc.x += v * xv.x; acc.y += v * xv.y;
  }
  *(float2*)(Agg + (size_t)d * (R * 128) + r * 128 + lane * 2) = acc;
}

// ---------------- weight pre-split: Wcat[128 n][512 k] -> hi/lo bf16 ----------------
// k<128 -> Wself[n][k]; else relation q=(k-128)>>7: Wrels[q][n][k&127]

__global__ __launch_bounds__(256)
void split_w_kernel(const float* __restrict__ Wself, const float* __restrict__ Wrels,
                    u16* __restrict__ Whi, u16* __restrict__ Wlo) {
  int e = (blockIdx.x * 256 + threadIdx.x) * 4;   // 65536 elems total
  if (e >= 128 * 512) return;
  int n = e >> 9;
  int k = e & 511;
  #pragma unroll
  for (int j = 0; j < 4; ++j) {
    int kk = k + j;
    float v;
    if (kk < 128) v = Wself[n * 128 + kk];
    else {
      int q = (kk - 128) >> 7;
      v = Wrels[q * 16384 + n * 128 + ((kk - 128) & 127)];
    }
    u16 h, l;
    split2(v, h, l);
    Whi[n * 512 + kk] = h;
    Wlo[n * 512 + kk] = l;
  }
}

// ---------------- MFMA GEMM: out = [x|Agg] @ Wcat^T + b via hi/lo split ----------------
// Block: 128 (M) x 128 (N=D_OUT). 4 waves in 2x2; each wave 64x64 = 4x4 16x16 frags.
// K = 512 fp32 in 16 phases of 32. Per phase: 3 MFMA terms (hh, lh, hl).

__global__ __launch_bounds__(256)
void gemm_mfma(const float* __restrict__ x, const float* __restrict__ Agg,
               const u16* __restrict__ Whi, const u16* __restrict__ Wlo,
               const float* __restrict__ bias, float* __restrict__ out, int N) {
  __shared__ __align__(16) u16 Ah[128][40];   // pad 40: frag reads <=2-way bank alias
  __shared__ __align__(16) u16 Al[128][40];
  __shared__ __align__(16) u16 Bh[128][40];
  __shared__ __align__(16) u16 Bl[128][40];

  const int m0   = blockIdx.x * 128;
  const int t    = threadIdx.x;
  const int lane = t & 63;
  const int wave = t >> 6;
  const int wm   = wave >> 1;       // 0..1  (M half)
  const int wn   = wave & 1;        // 0..1  (N half)
  const int lr   = lane & 15;       // row/col within 16
  const int kg   = lane >> 4;       // k-group 0..3 (8 bf16 each)

  f32x4 acc[4][4];
  #pragma unroll
  for (int i = 0; i < 4; ++i)
    #pragma unroll
    for (int j = 0; j < 4; ++j)
      #pragma unroll
      for (int c = 0; c < 4; ++c) acc[i][j][c] = 0.f;

  for (int ph = 0; ph < 16; ++ph) {
    __syncthreads();   // protect previous phase's tiles
    // ---- stage A (x or Agg): 128 rows x 32 fp32 -> hi/lo bf16 ----
    #pragma unroll
    for (int i = 0; i < 4; ++i) {
      int L   = t + i * 256;          // 0..1023
      int row = L >> 3;               // 0..127
      int c4  = L & 7;                // float4 index within 32 cols
      int gm  = m0 + row;
      float4 v = make_float4(0.f, 0.f, 0.f, 0.f);
      if (gm < N) {
        const float* Ap = (ph < 4) ? (x + (size_t)gm * 128 + ph * 32)
                                   : (Agg + (size_t)gm * 384 + (ph - 4) * 32);
        v = *(const float4*)(Ap + c4 * 4);
      }
      ushort4 h4, l4;
      split2(v.x, h4.x, l4.x);
      split2(v.y, h4.y, l4.y);
      split2(v.z, h4.z, l4.z);
      split2(v.w, h4.w, l4.w);
      *(ushort4*)&Ah[row][c4 * 4] = h4;
      *(ushort4*)&Al[row][c4 * 4] = l4;
    }
    // ---- stage B (pre-split weights): 128 n-rows x 32 k bf16 ----
    #pragma unroll
    for (int i = 0; i < 4; ++i) {
      int L   = t + i * 256;
      int row = L >> 3;
      int c4  = L & 7;                // ushort4 index within 32 k
      *(ushort4*)&Bh[row][c4 * 4] = *(const ushort4*)(Whi + row * 512 + ph * 32 + c4 * 4);
      *(ushort4*)&Bl[row][c4 * 4] = *(const ushort4*)(Wlo + row * 512 + ph * 32 + c4 * 4);
    }
    __syncthreads();

    // ---- fragments + MFMA ----
    bf16x8 ah[4], al[4], bh[4], bl[4];
    #pragma unroll
    for (int i = 0; i < 4; ++i) {
      ah[i] = *(const bf16x8*)&Ah[wm * 64 + i * 16 + lr][kg * 8];
      al[i] = *(const bf16x8*)&Al[wm * 64 + i * 16 + lr][kg * 8];
      bh[i] = *(const bf16x8*)&Bh[wn * 64 + i * 16 + lr][kg * 8];
      bl[i] = *(const bf16x8*)&Bl[wn * 64 + i * 16 + lr][kg * 8];
    }
    #pragma unroll
    for (int i = 0; i < 4; ++i)
      #pragma unroll
      for (int j = 0; j < 4; ++j) {
        acc[i][j] = __builtin_amdgcn_mfma_f32_16x16x32_bf16(ah[i], bh[j], acc[i][j], 0, 0, 0);
        acc[i][j] = __builtin_amdgcn_mfma_f32_16x16x32_bf16(al[i], bh[j], acc[i][j], 0, 0, 0);
        acc[i][j] = __builtin_amdgcn_mfma_f32_16x16x32_bf16(ah[i], bl[j], acc[i][j], 0, 0, 0);
      }
  }

  // ---- epilogue: C/D layout col=lane&15, row=(lane>>4)*4+reg (m89/m91) ----
  float bv[4];
  #pragma unroll
  for (int j = 0; j < 4; ++j) bv[j] = bias[wn * 64 + j * 16 + lr];
  #pragma unroll
  for (int i = 0; i < 4; ++i) {
    #pragma unroll
    for (int j = 0; j < 4; ++j) {
      int col = wn * 64 + j * 16 + lr;
      #pragma unroll
      for (int rg = 0; rg < 4; ++rg) {
        int gm = m0 + wm * 64 + i * 16 + kg * 4 + rg;
        if (gm < N) out[(size_t)gm * 128 + col] = acc[i][j][rg] + bv[j];
      }
    }
  }
}

// ---------------- fallback path (round-1, proven) ----------------

__global__ __launch_bounds__(256, 4)
void gemm_kernel(const float* __restrict__ x, const float* __restrict__ Wself,
                 const float* __restrict__ Wrels, const float* __restrict__ bias,
                 float* __restrict__ out, float* __restrict__ Y, int N, int R) {
  __shared__ float xs[64][68];
  __shared__ float ws[64][68];
  const int m0 = blockIdx.x * 64;
  const int nt = blockIdx.y;
  const float* Wp = (nt < 2) ? (Wself + nt * 64 * 128)
                             : (Wrels + (size_t)(nt - 2) * 64 * 128);
  const int t  = threadIdx.x;
  const int tm = t >> 4;
  const int tn = t & 15;
  float acc[4][4] = {};
  for (int ph = 0; ph < 2; ++ph) {
    __syncthreads();
    #pragma unroll
    for (int i = 0; i < 4; ++i) {
      int L = t + i * 256;
      int row = L >> 4;
      int c4 = L & 15;
      int gm = m0 + row;
      float4 xv = make_float4(0.f, 0.f, 0.f, 0.f);
      if (gm < N) xv = ((const float4*)(x + (size_t)gm * 128 + ph * 64))[c4];
      *((float4*)&xs[row][c4 * 4]) = xv;
      float4 wv = ((const float4*)(Wp + (size_t)row * 128 + ph * 64))[c4];
      *((float4*)&ws[row][c4 * 4]) = wv;
    }
    __syncthreads();
    #pragma unroll
    for (int kk = 0; kk < 16; ++kk) {
      float4 a[4], b[4];
      #pragma unroll
      for (int i = 0; i < 4; ++i) a[i] = *(const float4*)&xs[i * 16 + tm][kk * 4];
      #pragma unroll
      for (int j = 0; j < 4; ++j) b[j] = *(const float4*)&ws[j * 16 + tn][kk * 4];
      #pragma unroll
      for (int i = 0; i < 4; ++i)
        #pragma unroll
        for (int j = 0; j < 4; ++j) {
          acc[i][j] += a[i].x * b[j].x;
          acc[i][j] += a[i].y * b[j].y;
          acc[i][j] += a[i].z * b[j].z;
          acc[i][j] += a[i].w * b[j].w;
        }
    }
  }
  const int YS = R * 128;
  #pragma unroll
  for (int i = 0; i < 4; ++i) {
    int gm = m0 + i * 16 + tm;
    if (gm >= N) continue;
    #pragma unroll
    for (int j = 0; j < 4; ++j) {
      int col = j * 16 + tn;
      float v = acc[i][j];
      if (nt < 2) {
        int oc = nt * 64 + col;
        out[(size_t)gm * 128 + oc] = v + bias[oc];
      } else {
        int q = nt - 2;
        Y[(size_t)gm * YS + q * 64 + col] = v;
      }
    }
  }
}

__global__ __launch_bounds__(256)
void scatter_kernel(const float* __restrict__ Y, const int* __restrict__ src,
                    const int* __restrict__ dst, const float* __restrict__ vals,
                    float* __restrict__ out, long long total_slots, int E, int YS4) {
  long long tid = (long long)blockIdx.x * 256 + threadIdx.x;
  long long slot = tid >> 5;
  int lane = (int)(tid & 31);
  if (slot >= total_slots) return;
  int r = (int)(slot / E);
  int s = src[slot];
  int d = dst[slot];
  float v = vals[slot];
  float4 y = ((const float4*)Y)[(size_t)s * YS4 + r * 32 + lane];
  float* o = out + (size_t)d * 128 + lane * 4;
  atomicAdd(o + 0, v * y.x);
  atomicAdd(o + 1, v * y.y);
  atomicAdd(o + 2, v * y.z);
  atomicAdd(o + 3, v * y.w);
}

// ---------------- launch ----------------

extern "C" void kernel_launch(void* const* d_in, const int* in_sizes, int n_in,
                              void* d_out, int out_size, void* d_ws, size_t ws_size,
                              hipStream_t stream) {
  const float* x     = (const float*)d_in[0];
  const int*   src   = (const int*)d_in[1];
  const int*   dst   = (const int*)d_in[2];
  const float* vals  = (const float*)d_in[3];
  const float* Wself = (const float*)d_in[4];
  const float* bias  = (const float*)d_in[5];
  const float* Wrels = (const float*)d_in[6];
  float*       out   = (float*)d_out;

  const int N = in_sizes[0] / 128;
  const int R = in_sizes[6] / (128 * 128);
  const int E = in_sizes[1] / R;
  const int total = R * E;
  const int keys = R * N;
  const int nb = (keys + 1023) / 1024;

  // workspace layout (fast path)
  size_t aggBytes  = (size_t)N * R * 128 * sizeof(float);
  size_t curBytes  = ((size_t)keys * sizeof(int) + 255) & ~(size_t)255;
  size_t edgeBytes = ((size_t)total * sizeof(int2) + 255) & ~(size_t)255;
  size_t bsBytes   = ((size_t)nb * sizeof(int) + 255) & ~(size_t)255;
  size_t wBytes    = ((size_t)128 * 512 * sizeof(u16) + 255) & ~(size_t)255;
  size_t need = aggBytes + curBytes + edgeBytes + bsBytes + 2 * wBytes + 512;

  if (ws_size >= need && R == 3 && nb <= 1024 && (keys % 4) == 0) {
    char* base = (char*)d_ws;
    float* Agg       = (float*)base;  base += aggBytes;
    int*   cursor    = (int*)base;    base += curBytes;
    int*   blockSums = (int*)base;    base += bsBytes;
    int2*  edges     = (int2*)base;   base += edgeBytes;
    u16*   Whi       = (u16*)base;    base += wBytes;
    u16*   Wlo       = (u16*)base;

    hipMemsetAsync(cursor, 0, (size_t)keys * sizeof(int), stream);
    hist_kernel<<<(total + 255) / 256, 256, 0, stream>>>(dst, cursor, total, N, E);
    scanA_kernel<<<nb, 256, 0, stream>>>(cursor, blockSums, keys);
    scanB_kernel<<<1, 1024, 0, stream>>>(blockSums, nb);
    scanC_kernel<<<nb, 256, 0, stream>>>(cursor, blockSums, keys);
    fill_kernel<<<(total + 255) / 256, 256, 0, stream>>>(dst, src, vals, cursor, edges, total, N, E);
    split_w_kernel<<<64, 256, 0, stream>>>(Wself, Wrels, Whi, Wlo);
    aggregate_kernel<<<(keys + 3) / 4, 256, 0, stream>>>(x, edges, cursor, Agg, N, R, keys);
    gemm_mfma<<<(N + 127) / 128, 256, 0, stream>>>(x, Agg, Whi, Wlo, bias, out, N);
  } else {
    // fallback: dense Y + atomic scatter (round-1 path)
    float* Y = (float*)d_ws;
    dim3 g1((N + 63) / 64, 2 + 2 * R);
    gemm_kernel<<<g1, 256, 0, stream>>>(x, Wself, Wrels, bias, out, Y, N, R);
    long long slots = (long long)R * E;
    long long threads = slots * 32;
    int blocks = (int)((threads + 255) / 256);
    scatter_kernel<<<blocks, 256, 0, stream>>>(Y, src, dst, vals, out, slots, E, R * 32);
  }
}

// Round 10
// 537.155 us; speedup vs baseline: 6.1896x; 1.0377x over previous
//
#include <hip/hip_runtime.h>

// out = x@W_self^T + b + sum_r segment_sum(vals_r * x[src_r]) @ W_r^T
// CSR by (r,dst) -> 2-edge-per-wave register aggregation writing PRE-SPLIT
// bf16 hi/lo Agg -> MFMA GEMM (BK=64, global_load_lds + XOR-swizzle LDS,
// hh+lh+hl split terms) : out = [x|Agg] @ Wcat^T + b.

typedef __attribute__((ext_vector_type(8))) short bf16x8;
typedef __attribute__((ext_vector_type(4))) float f32x4;
typedef unsigned short u16;

__device__ inline void split2(float v, u16& h, u16& l) {
  unsigned u = __float_as_uint(v);
  u16 hu = (u16)(u >> 16);                       // truncate-to-bf16 hi
  float r = v - __uint_as_float((unsigned)hu << 16);
  unsigned ur = __float_as_uint(r);
  l = (u16)((ur + 0x7FFF + ((ur >> 16) & 1)) >> 16);  // RNE bf16 lo
  h = hu;
}

__device__ inline void gload_lds16(const void* g, void* lds) {
  __builtin_amdgcn_global_load_lds(
      (const __attribute__((address_space(1))) unsigned*)g,
      (__attribute__((address_space(3))) unsigned*)lds, 16, 0, 0);
}

// ---------------- CSR build ----------------

__global__ void hist_kernel(const int* __restrict__ dst, int* __restrict__ cursor,
                            int total, int N, int E) {
  int i = blockIdx.x * 256 + threadIdx.x;
  if (i >= total) return;
  int r = i / E;
  atomicAdd(&cursor[r * N + dst[i]], 1);
}

__global__ __launch_bounds__(256)
void scanA_kernel(const int* __restrict__ cursor, int* __restrict__ blockSums, int keys) {
  int t = threadIdx.x;
  int idx = blockIdx.x * 1024 + t * 4;
  int s = 0;
  if (idx < keys) {
    int4 v = *(const int4*)(cursor + idx);
    s = v.x + v.y + v.z + v.w;
  }
  __shared__ int lds[256];
  lds[t] = s;
  __syncthreads();
  for (int off = 128; off > 0; off >>= 1) {
    if (t < off) lds[t] += lds[t + off];
    __syncthreads();
  }
  if (t == 0) blockSums[blockIdx.x] = lds[0];
}

__global__ __launch_bounds__(1024)
void scanB_kernel(int* __restrict__ blockSums, int nb) {
  __shared__ int lds[1024];
  int t = threadIdx.x;
  int v0 = (t < nb) ? blockSums[t] : 0;
  lds[t] = v0;
  __syncthreads();
  for (int off = 1; off < 1024; off <<= 1) {
    int v = (t >= off) ? lds[t - off] : 0;
    __syncthreads();
    lds[t] += v;
    __syncthreads();
  }
  if (t < nb) blockSums[t] = lds[t] - v0;  // exclusive
}

__global__ __launch_bounds__(256)
void scanC_kernel(int* __restrict__ cursor, const int* __restrict__ blockSums, int keys) {
  int t = threadIdx.x;
  int idx = blockIdx.x * 1024 + t * 4;
  int4 v = make_int4(0, 0, 0, 0);
  if (idx < keys) v = *(const int4*)(cursor + idx);
  int s = v.x + v.y + v.z + v.w;
  __shared__ int lds[256];
  lds[t] = s;
  __syncthreads();
  for (int off = 1; off < 256; off <<= 1) {
    int u = (t >= off) ? lds[t - off] : 0;
    __syncthreads();
    lds[t] += u;
    __syncthreads();
  }
  int run = blockSums[blockIdx.x] + lds[t] - s;
  if (idx < keys) {
    int4 o;
    o.x = run;              run += v.x;
    o.y = run;              run += v.y;
    o.z = run;              run += v.z;
    o.w = run;
    *(int4*)(cursor + idx) = o;
  }
}

__global__ void fill_kernel(const int* __restrict__ dst, const int* __restrict__ src,
                            const float* __restrict__ vals, int* __restrict__ cursor,
                            int2* __restrict__ edges, int total, int N, int E) {
  int i = blockIdx.x * 256 + threadIdx.x;
  if (i >= total) return;
  int r = i / E;
  int key = r * N + dst[i];
  int p = atomicAdd(&cursor[key], 1);
  edges[p] = make_int2(src[i], __float_as_int(vals[i]));
}

// ---------------- aggregation: 2 edges/wave, writes hi/lo bf16 Agg ----------------
// lanes 0-31 = edge stream 0, lanes 32-63 = edge stream 1; float4/lane (512B row).
// Final __shfl_xor(32) combine; sub0 writes Agg_hi, sub1 writes Agg_lo.

__global__ __launch_bounds__(256)
void aggregate_kernel(const float* __restrict__ x, const int2* __restrict__ edges,
                      const int* __restrict__ cursor, u16* __restrict__ Agghi,
                      u16* __restrict__ Agglo, int N, int keys) {
  int wid = blockIdx.x * 4 + (threadIdx.x >> 6);
  if (wid >= keys) return;
  int lane    = threadIdx.x & 63;
  int lane_in = lane & 31;
  int sub     = lane >> 5;
  int r = (wid < N) ? 0 : ((wid < 2 * N) ? 1 : 2);
  int d = wid - r * N;
  int pstart = (wid == 0) ? 0 : cursor[wid - 1];
  int pend   = cursor[wid];
  float4 acc = make_float4(0.f, 0.f, 0.f, 0.f);
  int p = pstart + sub;
  // 4 edges in flight per sub-stream (8 per wave)
  for (; p + 6 < pend; p += 8) {
    int2 e0 = edges[p + 0];
    int2 e1 = edges[p + 2];
    int2 e2 = edges[p + 4];
    int2 e3 = edges[p + 6];
    float4 x0 = *(const float4*)(x + (size_t)e0.x * 128 + lane_in * 4);
    float4 x1 = *(const float4*)(x + (size_t)e1.x * 128 + lane_in * 4);
    float4 x2 = *(const float4*)(x + (size_t)e2.x * 128 + lane_in * 4);
    float4 x3 = *(const float4*)(x + (size_t)e3.x * 128 + lane_in * 4);
    float v0 = __int_as_float(e0.y), v1 = __int_as_float(e1.y);
    float v2 = __int_as_float(e2.y), v3 = __int_as_float(e3.y);
    acc.x += v0 * x0.x; acc.y += v0 * x0.y; acc.z += v0 * x0.z; acc.w += v0 * x0.w;
    acc.x += v1 * x1.x; acc.y += v1 * x1.y; acc.z += v1 * x1.z; acc.w += v1 * x1.w;
    acc.x += v2 * x2.x; acc.y += v2 * x2.y; acc.z += v2 * x2.z; acc.w += v2 * x2.w;
    acc.x += v3 * x3.x; acc.y += v3 * x3.y; acc.z += v3 * x3.z; acc.w += v3 * x3.w;
  }
  for (; p < pend; p += 2) {
    int2 e = edges[p];
    float4 xv = *(const float4*)(x + (size_t)e.x * 128 + lane_in * 4);
    float v = __int_as_float(e.y);
    acc.x += v * xv.x; acc.y += v * xv.y; acc.z += v * xv.z; acc.w += v * xv.w;
  }
  // combine the two sub-streams (both halves end with the total)
  acc.x += __shfl_xor(acc.x, 32);
  acc.y += __shfl_xor(acc.y, 32);
  acc.z += __shfl_xor(acc.z, 32);
  acc.w += __shfl_xor(acc.w, 32);
  u16 h0, l0, h1, l1, h2, l2, h3, l3;
  split2(acc.x, h0, l0); split2(acc.y, h1, l1);
  split2(acc.z, h2, l2); split2(acc.w, h3, l3);
  ushort4 w4;
  if (sub) { w4.x = l0; w4.y = l1; w4.z = l2; w4.w = l3; }
  else     { w4.x = h0; w4.y = h1; w4.z = h2; w4.w = h3; }
  u16* dstp = (sub ? Agglo : Agghi) + (size_t)d * 384 + r * 128 + lane_in * 4;
  *(ushort4*)dstp = w4;
}

// ---------------- weight pre-split: Wcat[128 n][512 k] -> hi/lo bf16 ----------------

__global__ __launch_bounds__(256)
void split_w_kernel(const float* __restrict__ Wself, const float* __restrict__ Wrels,
                    u16* __restrict__ Whi, u16* __restrict__ Wlo) {
  int e = (blockIdx.x * 256 + threadIdx.x) * 4;   // 65536 elems total
  if (e >= 128 * 512) return;
  int n = e >> 9;
  int k = e & 511;
  #pragma unroll
  for (int j = 0; j < 4; ++j) {
    int kk = k + j;
    float v;
    if (kk < 128) v = Wself[n * 128 + kk];
    else {
      int q = (kk - 128) >> 7;
      v = Wrels[q * 16384 + n * 128 + ((kk - 128) & 127)];
    }
    u16 h, l;
    split2(v, h, l);
    Whi[n * 512 + kk] = h;
    Wlo[n * 512 + kk] = l;
  }
}

// ---------------- MFMA GEMM: out = [x|Agg] @ Wcat^T + b (hh+lh+hl) ----------------
// 128x128 block, 4 waves 2x2, BK=64, 8 phases. LDS tiles [128 rows][8 chunks of 16B],
// linear, XOR-swizzled: slot s of row holds logical chunk s^(row&7).
// Agg/W staged by global_load_lds (pre-swizzled source addr); x phases reg-staged+split.

__global__ __launch_bounds__(256)
void gemm_mfma(const float* __restrict__ x, const u16* __restrict__ Agghi,
               const u16* __restrict__ Agglo, const u16* __restrict__ Whi,
               const u16* __restrict__ Wlo, const float* __restrict__ bias,
               float* __restrict__ out, int N) {
  __shared__ __align__(16) u16 Ah[128 * 64];
  __shared__ __align__(16) u16 Al[128 * 64];
  __shared__ __align__(16) u16 Bh[128 * 64];
  __shared__ __align__(16) u16 Bl[128 * 64];

  const int m0   = blockIdx.x * 128;
  const int t    = threadIdx.x;
  const int lane = t & 63;
  const int wave = t >> 6;
  const int wm   = wave >> 1;
  const int wn   = wave & 1;
  const int lr   = lane & 15;
  const int kg   = lane >> 4;

  f32x4 acc[4][4];
  #pragma unroll
  for (int i = 0; i < 4; ++i)
    #pragma unroll
    for (int j = 0; j < 4; ++j)
      #pragma unroll
      for (int c = 0; c < 4; ++c) acc[i][j][c] = 0.f;

  for (int ph = 0; ph < 8; ++ph) {
    __syncthreads();   // previous phase's frag reads complete

    // ---- stage B (Whi/Wlo) via global_load_lds, swizzled source ----
    #pragma unroll
    for (int j = 0; j < 8; ++j) {
      int p    = wave * 8 + j;          // 0..31
      int tile = p >> 4;                // 0: Bh, 1: Bl
      int rg   = p & 15;
      int row  = rg * 8 + (lane >> 3);
      int c16  = (lane & 7) ^ (row & 7);
      const u16* gsrc = (tile ? Wlo : Whi) + row * 512 + ph * 64 + c16 * 8;
      u16* ldst = (tile ? Bl : Bh) + rg * 512 + lane * 8;
      gload_lds16(gsrc, ldst);
    }
    if (ph >= 2) {
      // ---- stage A from pre-split Agg via global_load_lds ----
      int kofs = ph * 64 - 128;
      #pragma unroll
      for (int j = 0; j < 8; ++j) {
        int p    = wave * 8 + j;
        int tile = p >> 4;              // 0: Ah, 1: Al
        int rg   = p & 15;
        int row  = rg * 8 + (lane >> 3);
        int grow = m0 + row; if (grow > N - 1) grow = N - 1;   // clamp, masked at store
        int c16  = (lane & 7) ^ (row & 7);
        const u16* gsrc = (tile ? Agglo : Agghi) + (size_t)grow * 384 + kofs + c16 * 8;
        u16* ldst = (tile ? Al : Ah) + rg * 512 + lane * 8;
        gload_lds16(gsrc, ldst);
      }
    } else {
      // ---- stage A from fp32 x: reg load + split + swizzled ds_write ----
      #pragma unroll
      for (int i = 0; i < 4; ++i) {
        int q   = t + i * 256;          // 0..1023
        int row = q >> 3;
        int c16 = q & 7;
        int gm  = m0 + row;
        float4 va = make_float4(0.f, 0.f, 0.f, 0.f);
        float4 vb = make_float4(0.f, 0.f, 0.f, 0.f);
        if (gm < N) {
          const float* xp = x + (size_t)gm * 128 + ph * 64 + c16 * 8;
          va = *(const float4*)xp;
          vb = *(const float4*)(xp + 4);
        }
        ushort4 ha, la, hb, lb;
        split2(va.x, ha.x, la.x); split2(va.y, ha.y, la.y);
        split2(va.z, ha.z, la.z); split2(va.w, ha.w, la.w);
        split2(vb.x, hb.x, lb.x); split2(vb.y, hb.y, lb.y);
        split2(vb.z, hb.z, lb.z); split2(vb.w, hb.w, lb.w);
        int slot = c16 ^ (row & 7);
        int idx = row * 64 + slot * 8;
        *(ushort4*)&Ah[idx]     = ha;
        *(ushort4*)&Ah[idx + 4] = hb;
        *(ushort4*)&Al[idx]     = la;
        *(ushort4*)&Al[idx + 4] = lb;
      }
    }
    __syncthreads();   // vmcnt(0)+lgkmcnt(0) drain before reads

    // ---- fragments (swizzled read) + MFMA ----
    bf16x8 ah[4][2], al[4][2], bh[4][2], bl[4][2];
    #pragma unroll
    for (int i = 0; i < 4; ++i) {
      int arow = wm * 64 + i * 16 + lr;
      int brow = wn * 64 + i * 16 + lr;
      #pragma unroll
      for (int ks = 0; ks < 2; ++ks) {
        int ac = ((ks * 4 + kg) ^ (arow & 7)) * 8;
        int bc = ((ks * 4 + kg) ^ (brow & 7)) * 8;
        ah[i][ks] = *(const bf16x8*)&Ah[arow * 64 + ac];
        al[i][ks] = *(const bf16x8*)&Al[arow * 64 + ac];
        bh[i][ks] = *(const bf16x8*)&Bh[brow * 64 + bc];
        bl[i][ks] = *(const bf16x8*)&Bl[brow * 64 + bc];
      }
    }
    #pragma unroll
    for (int i = 0; i < 4; ++i)
      #pragma unroll
      for (int j = 0; j < 4; ++j)
        #pragma unroll
        for (int ks = 0; ks < 2; ++ks) {
          acc[i][j] = __builtin_amdgcn_mfma_f32_16x16x32_bf16(ah[i][ks], bh[j][ks], acc[i][j], 0, 0, 0);
          acc[i][j] = __builtin_amdgcn_mfma_f32_16x16x32_bf16(al[i][ks], bh[j][ks], acc[i][j], 0, 0, 0);
          acc[i][j] = __builtin_amdgcn_mfma_f32_16x16x32_bf16(ah[i][ks], bl[j][ks], acc[i][j], 0, 0, 0);
        }
  }

  // ---- epilogue: C/D col=lane&15, row=(lane>>4)*4+reg (m89/m91) ----
  float bv[4];
  #pragma unroll
  for (int j = 0; j < 4; ++j) bv[j] = bias[wn * 64 + j * 16 + lr];
  #pragma unroll
  for (int i = 0; i < 4; ++i) {
    #pragma unroll
    for (int j = 0; j < 4; ++j) {
      int col = wn * 64 + j * 16 + lr;
      #pragma unroll
      for (int rg = 0; rg < 4; ++rg) {
        int gm = m0 + wm * 64 + i * 16 + kg * 4 + rg;
        if (gm < N) out[(size_t)gm * 128 + col] = acc[i][j][rg] + bv[j];
      }
    }
  }
}

// ---------------- fallback path (round-1, proven) ----------------

__global__ __launch_bounds__(256, 4)
void gemm_kernel(const float* __restrict__ x, const float* __restrict__ Wself,
                 const float* __restrict__ Wrels, const float* __restrict__ bias,
                 float* __restrict__ out, float* __restrict__ Y, int N, int R) {
  __shared__ float xs[64][68];
  __shared__ float ws[64][68];
  const int m0 = blockIdx.x * 64;
  const int nt = blockIdx.y;
  const float* Wp = (nt < 2) ? (Wself + nt * 64 * 128)
                             : (Wrels + (size_t)(nt - 2) * 64 * 128);
  const int t  = threadIdx.x;
  const int tm = t >> 4;
  const int tn = t & 15;
  float acc[4][4] = {};
  for (int ph = 0; ph < 2; ++ph) {
    __syncthreads();
    #pragma unroll
    for (int i = 0; i < 4; ++i) {
      int L = t + i * 256;
      int row = L >> 4;
      int c4 = L & 15;
      int gm = m0 + row;
      float4 xv = make_float4(0.f, 0.f, 0.f, 0.f);
      if (gm < N) xv = ((const float4*)(x + (size_t)gm * 128 + ph * 64))[c4];
      *((float4*)&xs[row][c4 * 4]) = xv;
      float4 wv = ((const float4*)(Wp + (size_t)row * 128 + ph * 64))[c4];
      *((float4*)&ws[row][c4 * 4]) = wv;
    }
    __syncthreads();
    #pragma unroll
    for (int kk = 0; kk < 16; ++kk) {
      float4 a[4], b[4];
      #pragma unroll
      for (int i = 0; i < 4; ++i) a[i] = *(const float4*)&xs[i * 16 + tm][kk * 4];
      #pragma unroll
      for (int j = 0; j < 4; ++j) b[j] = *(const float4*)&ws[j * 16 + tn][kk * 4];
      #pragma unroll
      for (int i = 0; i < 4; ++i)
        #pragma unroll
        for (int j = 0; j < 4; ++j) {
          acc[i][j] += a[i].x * b[j].x;
          acc[i][j] += a[i].y * b[j].y;
          acc[i][j] += a[i].z * b[j].z;
          acc[i][j] += a[i].w * b[j].w;
        }
    }
  }
  const int YS = R * 128;
  #pragma unroll
  for (int i = 0; i < 4; ++i) {
    int gm = m0 + i * 16 + tm;
    if (gm >= N) continue;
    #pragma unroll
    for (int j = 0; j < 4; ++j) {
      int col = j * 16 + tn;
      float v = acc[i][j];
      if (nt < 2) {
        int oc = nt * 64 + col;
        out[(size_t)gm * 128 + oc] = v + bias[oc];
      } else {
        int q = nt - 2;
        Y[(size_t)gm * YS + q * 64 + col] = v;
      }
    }
  }
}

__global__ __launch_bounds__(256)
void scatter_kernel(const float* __restrict__ Y, const int* __restrict__ src,
                    const int* __restrict__ dst, const float* __restrict__ vals,
                    float* __restrict__ out, long long total_slots, int E, int YS4) {
  long long tid = (long long)blockIdx.x * 256 + threadIdx.x;
  long long slot = tid >> 5;
  int lane = (int)(tid & 31);
  if (slot >= total_slots) return;
  int r = (int)(slot / E);
  int s = src[slot];
  int d = dst[slot];
  float v = vals[slot];
  float4 y = ((const float4*)Y)[(size_t)s * YS4 + r * 32 + lane];
  float* o = out + (size_t)d * 128 + lane * 4;
  atomicAdd(o + 0, v * y.x);
  atomicAdd(o + 1, v * y.y);
  atomicAdd(o + 2, v * y.z);
  atomicAdd(o + 3, v * y.w);
}

// ---------------- launch ----------------

extern "C" void kernel_launch(void* const* d_in, const int* in_sizes, int n_in,
                              void* d_out, int out_size, void* d_ws, size_t ws_size,
                              hipStream_t stream) {
  const float* x     = (const float*)d_in[0];
  const int*   src   = (const int*)d_in[1];
  const int*   dst   = (const int*)d_in[2];
  const float* vals  = (const float*)d_in[3];
  const float* Wself = (const float*)d_in[4];
  const float* bias  = (const float*)d_in[5];
  const float* Wrels = (const float*)d_in[6];
  float*       out   = (float*)d_out;

  const int N = in_sizes[0] / 128;
  const int R = in_sizes[6] / (128 * 128);
  const int E = in_sizes[1] / R;
  const int total = R * E;
  const int keys = R * N;
  const int nb = (keys + 1023) / 1024;

  // workspace layout (fast path)
  size_t aggBytes  = (((size_t)N * R * 128 * sizeof(u16)) + 255) & ~(size_t)255;  // per hi/lo
  size_t curBytes  = ((size_t)keys * sizeof(int) + 255) & ~(size_t)255;
  size_t edgeBytes = ((size_t)total * sizeof(int2) + 255) & ~(size_t)255;
  size_t bsBytes   = ((size_t)nb * sizeof(int) + 255) & ~(size_t)255;
  size_t wBytes    = ((size_t)128 * 512 * sizeof(u16) + 255) & ~(size_t)255;
  size_t need = 2 * aggBytes + curBytes + edgeBytes + bsBytes + 2 * wBytes + 512;

  if (ws_size >= need && R == 3 && nb <= 1024 && (keys % 4) == 0) {
    char* base = (char*)d_ws;
    u16*   Agghi     = (u16*)base;    base += aggBytes;
    u16*   Agglo     = (u16*)base;    base += aggBytes;
    int*   cursor    = (int*)base;    base += curBytes;
    int*   blockSums = (int*)base;    base += bsBytes;
    int2*  edges     = (int2*)base;   base += edgeBytes;
    u16*   Whi       = (u16*)base;    base += wBytes;
    u16*   Wlo       = (u16*)base;

    hipMemsetAsync(cursor, 0, (size_t)keys * sizeof(int), stream);
    hist_kernel<<<(total + 255) / 256, 256, 0, stream>>>(dst, cursor, total, N, E);
    scanA_kernel<<<nb, 256, 0, stream>>>(cursor, blockSums, keys);
    scanB_kernel<<<1, 1024, 0, stream>>>(blockSums, nb);
    scanC_kernel<<<nb, 256, 0, stream>>>(cursor, blockSums, keys);
    fill_kernel<<<(total + 255) / 256, 256, 0, stream>>>(dst, src, vals, cursor, edges, total, N, E);
    split_w_kernel<<<64, 256, 0, stream>>>(Wself, Wrels, Whi, Wlo);
    aggregate_kernel<<<(keys + 3) / 4, 256, 0, stream>>>(x, edges, cursor, Agghi, Agglo, N, keys);
    gemm_mfma<<<(N + 127) / 128, 256, 0, stream>>>(x, Agghi, Agglo, Whi, Wlo, bias, out, N);
  } else {
    // fallback: dense Y + atomic scatter (round-1 path)
    float* Y = (float*)d_ws;
    dim3 g1((N + 63) / 64, 2 + 2 * R);
    gemm_kernel<<<g1, 256, 0, stream>>>(x, Wself, Wrels, bias, out, Y, N, R);
    long long slots = (long long)R * E;
    long long threads = slots * 32;
    int blocks = (int)((threads + 255) / 256);
    scatter_kernel<<<blocks, 256, 0, stream>>>(Y, src, dst, vals, out, slots, E, R * 32);
  }
}

// Round 12
// 516.077 us; speedup vs baseline: 6.4424x; 1.0408x over previous
//
#include <hip/hip_runtime.h>

// out = x@W_self^T + b + sum_r segment_sum(vals_r * x[src_r]) @ W_r^T
// CSR by (r,dst) -> broadcast-edge aggregation (1 vector edge-load per 64 edges,
// 8 x-row gathers in flight) writing PRE-SPLIT bf16 hi/lo Agg -> MFMA GEMM
// (BK=64, global_load_lds + XOR-swizzle LDS, hh+lh+hl) : out = [x|Agg]@Wcat^T + b.

typedef __attribute__((ext_vector_type(8))) short bf16x8;
typedef __attribute__((ext_vector_type(4))) float f32x4;
typedef unsigned short u16;

__device__ inline void split2(float v, u16& h, u16& l) {
  unsigned u = __float_as_uint(v);
  u16 hu = (u16)(u >> 16);                       // truncate-to-bf16 hi
  float r = v - __uint_as_float((unsigned)hu << 16);
  unsigned ur = __float_as_uint(r);
  l = (u16)((ur + 0x7FFF + ((ur >> 16) & 1)) >> 16);  // RNE bf16 lo
  h = hu;
}

__device__ inline void gload_lds16(const void* g, void* lds) {
  __builtin_amdgcn_global_load_lds(
      (const __attribute__((address_space(1))) unsigned*)g,
      (__attribute__((address_space(3))) unsigned*)lds, 16, 0, 0);
}

// ---------------- CSR build ----------------

__global__ void hist_kernel(const int* __restrict__ dst, int* __restrict__ cursor,
                            int total, int N, int E) {
  int i = blockIdx.x * 256 + threadIdx.x;
  if (i >= total) return;
  int r = i / E;
  atomicAdd(&cursor[r * N + dst[i]], 1);
}

__global__ __launch_bounds__(256)
void scanA_kernel(const int* __restrict__ cursor, int* __restrict__ blockSums, int keys) {
  int t = threadIdx.x;
  int idx = blockIdx.x * 1024 + t * 4;
  int s = 0;
  if (idx < keys) {
    int4 v = *(const int4*)(cursor + idx);
    s = v.x + v.y + v.z + v.w;
  }
  __shared__ int lds[256];
  lds[t] = s;
  __syncthreads();
  for (int off = 128; off > 0; off >>= 1) {
    if (t < off) lds[t] += lds[t + off];
    __syncthreads();
  }
  if (t == 0) blockSums[blockIdx.x] = lds[0];
}

__global__ __launch_bounds__(1024)
void scanB_kernel(int* __restrict__ blockSums, int nb) {
  __shared__ int lds[1024];
  int t = threadIdx.x;
  int v0 = (t < nb) ? blockSums[t] : 0;
  lds[t] = v0;
  __syncthreads();
  for (int off = 1; off < 1024; off <<= 1) {
    int v = (t >= off) ? lds[t - off] : 0;
    __syncthreads();
    lds[t] += v;
    __syncthreads();
  }
  if (t < nb) blockSums[t] = lds[t] - v0;  // exclusive
}

__global__ __launch_bounds__(256)
void scanC_kernel(int* __restrict__ cursor, const int* __restrict__ blockSums, int keys) {
  int t = threadIdx.x;
  int idx = blockIdx.x * 1024 + t * 4;
  int4 v = make_int4(0, 0, 0, 0);
  if (idx < keys) v = *(const int4*)(cursor + idx);
  int s = v.x + v.y + v.z + v.w;
  __shared__ int lds[256];
  lds[t] = s;
  __syncthreads();
  for (int off = 1; off < 256; off <<= 1) {
    int u = (t >= off) ? lds[t - off] : 0;
    __syncthreads();
    lds[t] += u;
    __syncthreads();
  }
  int run = blockSums[blockIdx.x] + lds[t] - s;
  if (idx < keys) {
    int4 o;
    o.x = run;              run += v.x;
    o.y = run;              run += v.y;
    o.z = run;              run += v.z;
    o.w = run;
    *(int4*)(cursor + idx) = o;
  }
}

__global__ void fill_kernel(const int* __restrict__ dst, const int* __restrict__ src,
                            const float* __restrict__ vals, int* __restrict__ cursor,
                            int2* __restrict__ edges, int total, int N, int E) {
  int i = blockIdx.x * 256 + threadIdx.x;
  if (i >= total) return;
  int r = i / E;
  int key = r * N + dst[i];
  int p = atomicAdd(&cursor[key], 1);
  edges[p] = make_int2(src[i], __float_as_int(vals[i]));
}

// ---------------- aggregation: broadcast edges, 8 gathers in flight ----------------
// One wave per (r,dst) key. Lane i loads edge record i of the segment (clamped),
// records are broadcast via __shfl; per round of 8 edges the wave issues 8
// independent 512B x-row loads (2 sub-streams x 4 float4/lane). v=0 for clamped.

__global__ __launch_bounds__(256)
void aggregate_kernel(const float* __restrict__ x, const int2* __restrict__ edges,
                      const int* __restrict__ cursor, u16* __restrict__ Agghi,
                      u16* __restrict__ Agglo, int N, int keys) {
  int wid = blockIdx.x * 4 + (threadIdx.x >> 6);
  if (wid >= keys) return;
  const int lane    = threadIdx.x & 63;
  const int lane_in = lane & 31;
  const int sub     = lane >> 5;
  int r = (wid < N) ? 0 : ((wid < 2 * N) ? 1 : 2);
  int d = wid - r * N;
  int pstart = (wid == 0) ? 0 : cursor[wid - 1];
  int len    = cursor[wid] - pstart;
  float4 acc = make_float4(0.f, 0.f, 0.f, 0.f);

  for (int base = 0; base < len; base += 64) {
    int rem  = len - base;                          // >= 1
    int eidx = (lane < rem) ? lane : (rem - 1);     // clamp: always valid record
    int2 myE = edges[pstart + base + eidx];         // one coalesced load / 64 edges
    int rounds = (rem < 64) ? rem : 64;
    for (int b = 0; b < rounds; b += 8) {
      int j0 = b + sub, j1 = b + 2 + sub, j2 = b + 4 + sub, j3 = b + 6 + sub;
      int s0 = __shfl(myE.x, j0);
      int s1 = __shfl(myE.x, j1);
      int s2 = __shfl(myE.x, j2);
      int s3 = __shfl(myE.x, j3);
      float v0 = (j0 < rem) ? __int_as_float(__shfl(myE.y, j0)) : 0.f;
      float v1 = (j1 < rem) ? __int_as_float(__shfl(myE.y, j1)) : 0.f;
      float v2 = (j2 < rem) ? __int_as_float(__shfl(myE.y, j2)) : 0.f;
      float v3 = (j3 < rem) ? __int_as_float(__shfl(myE.y, j3)) : 0.f;
      float4 x0 = *(const float4*)(x + (size_t)s0 * 128 + lane_in * 4);
      float4 x1 = *(const float4*)(x + (size_t)s1 * 128 + lane_in * 4);
      float4 x2 = *(const float4*)(x + (size_t)s2 * 128 + lane_in * 4);
      float4 x3 = *(const float4*)(x + (size_t)s3 * 128 + lane_in * 4);
      acc.x += v0 * x0.x; acc.y += v0 * x0.y; acc.z += v0 * x0.z; acc.w += v0 * x0.w;
      acc.x += v1 * x1.x; acc.y += v1 * x1.y; acc.z += v1 * x1.z; acc.w += v1 * x1.w;
      acc.x += v2 * x2.x; acc.y += v2 * x2.y; acc.z += v2 * x2.z; acc.w += v2 * x2.w;
      acc.x += v3 * x3.x; acc.y += v3 * x3.y; acc.z += v3 * x3.z; acc.w += v3 * x3.w;
    }
  }
  // combine the two sub-streams (both halves end with the total)
  acc.x += __shfl_xor(acc.x, 32);
  acc.y += __shfl_xor(acc.y, 32);
  acc.z += __shfl_xor(acc.z, 32);
  acc.w += __shfl_xor(acc.w, 32);
  u16 h0, l0, h1, l1, h2, l2, h3, l3;
  split2(acc.x, h0, l0); split2(acc.y, h1, l1);
  split2(acc.z, h2, l2); split2(acc.w, h3, l3);
  ushort4 w4;
  if (sub) { w4.x = l0; w4.y = l1; w4.z = l2; w4.w = l3; }
  else     { w4.x = h0; w4.y = h1; w4.z = h2; w4.w = h3; }
  u16* dstp = (sub ? Agglo : Agghi) + (size_t)d * 384 + r * 128 + lane_in * 4;
  *(ushort4*)dstp = w4;
}

// ---------------- weight pre-split: Wcat[128 n][512 k] -> hi/lo bf16 ----------------

__global__ __launch_bounds__(256)
void split_w_kernel(const float* __restrict__ Wself, const float* __restrict__ Wrels,
                    u16* __restrict__ Whi, u16* __restrict__ Wlo) {
  int e = (blockIdx.x * 256 + threadIdx.x) * 4;   // 65536 elems total
  if (e >= 128 * 512) return;
  int n = e >> 9;
  int k = e & 511;
  #pragma unroll
  for (int j = 0; j < 4; ++j) {
    int kk = k + j;
    float v;
    if (kk < 128) v = Wself[n * 128 + kk];
    else {
      int q = (kk - 128) >> 7;
      v = Wrels[q * 16384 + n * 128 + ((kk - 128) & 127)];
    }
    u16 h, l;
    split2(v, h, l);
    Whi[n * 512 + kk] = h;
    Wlo[n * 512 + kk] = l;
  }
}

// ---------------- MFMA GEMM: out = [x|Agg] @ Wcat^T + b (hh+lh+hl) ----------------
// 128x128 block, 4 waves 2x2, BK=64, 8 phases. LDS tiles [128 rows][8 chunks of 16B],
// linear, XOR-swizzled: slot s of row holds logical chunk s^(row&7).
// Agg/W staged by global_load_lds (pre-swizzled source addr); x phases reg-staged+split.

__global__ __launch_bounds__(256)
void gemm_mfma(const float* __restrict__ x, const u16* __restrict__ Agghi,
               const u16* __restrict__ Agglo, const u16* __restrict__ Whi,
               const u16* __restrict__ Wlo, const float* __restrict__ bias,
               float* __restrict__ out, int N) {
  __shared__ __align__(16) u16 Ah[128 * 64];
  __shared__ __align__(16) u16 Al[128 * 64];
  __shared__ __align__(16) u16 Bh[128 * 64];
  __shared__ __align__(16) u16 Bl[128 * 64];

  const int m0   = blockIdx.x * 128;
  const int t    = threadIdx.x;
  const int lane = t & 63;
  const int wave = t >> 6;
  const int wm   = wave >> 1;
  const int wn   = wave & 1;
  const int lr   = lane & 15;
  const int kg   = lane >> 4;

  f32x4 acc[4][4];
  #pragma unroll
  for (int i = 0; i < 4; ++i)
    #pragma unroll
    for (int j = 0; j < 4; ++j)
      #pragma unroll
      for (int c = 0; c < 4; ++c) acc[i][j][c] = 0.f;

  for (int ph = 0; ph < 8; ++ph) {
    __syncthreads();   // previous phase's frag reads complete

    // ---- stage B (Whi/Wlo) via global_load_lds, swizzled source ----
    #pragma unroll
    for (int j = 0; j < 8; ++j) {
      int p    = wave * 8 + j;          // 0..31
      int tile = p >> 4;                // 0: Bh, 1: Bl
      int rg   = p & 15;
      int row  = rg * 8 + (lane >> 3);
      int c16  = (lane & 7) ^ (row & 7);
      const u16* gsrc = (tile ? Wlo : Whi) + row * 512 + ph * 64 + c16 * 8;
      u16* ldst = (tile ? Bl : Bh) + rg * 512 + lane * 8;
      gload_lds16(gsrc, ldst);
    }
    if (ph >= 2) {
      // ---- stage A from pre-split Agg via global_load_lds ----
      int kofs = ph * 64 - 128;
      #pragma unroll
      for (int j = 0; j < 8; ++j) {
        int p    = wave * 8 + j;
        int tile = p >> 4;              // 0: Ah, 1: Al
        int rg   = p & 15;
        int row  = rg * 8 + (lane >> 3);
        int grow = m0 + row; if (grow > N - 1) grow = N - 1;   // clamp, masked at store
        int c16  = (lane & 7) ^ (row & 7);
        const u16* gsrc = (tile ? Agglo : Agghi) + (size_t)grow * 384 + kofs + c16 * 8;
        u16* ldst = (tile ? Al : Ah) + rg * 512 + lane * 8;
        gload_lds16(gsrc, ldst);
      }
    } else {
      // ---- stage A from fp32 x: reg load + split + swizzled ds_write ----
      #pragma unroll
      for (int i = 0; i < 4; ++i) {
        int q   = t + i * 256;          // 0..1023
        int row = q >> 3;
        int c16 = q & 7;
        int gm  = m0 + row;
        float4 va = make_float4(0.f, 0.f, 0.f, 0.f);
        float4 vb = make_float4(0.f, 0.f, 0.f, 0.f);
        if (gm < N) {
          const float* xp = x + (size_t)gm * 128 + ph * 64 + c16 * 8;
          va = *(const float4*)xp;
          vb = *(const float4*)(xp + 4);
        }
        ushort4 ha, la, hb, lb;
        split2(va.x, ha.x, la.x); split2(va.y, ha.y, la.y);
        split2(va.z, ha.z, la.z); split2(va.w, ha.w, la.w);
        split2(vb.x, hb.x, lb.x); split2(vb.y, hb.y, lb.y);
        split2(vb.z, hb.z, lb.z); split2(vb.w, hb.w, lb.w);
        int slot = c16 ^ (row & 7);
        int idx = row * 64 + slot * 8;
        *(ushort4*)&Ah[idx]     = ha;
        *(ushort4*)&Ah[idx + 4] = hb;
        *(ushort4*)&Al[idx]     = la;
        *(ushort4*)&Al[idx + 4] = lb;
      }
    }
    __syncthreads();   // vmcnt(0)+lgkmcnt(0) drain before reads

    // ---- fragments (swizzled read) + MFMA ----
    bf16x8 ah[4][2], al[4][2], bh[4][2], bl[4][2];
    #pragma unroll
    for (int i = 0; i < 4; ++i) {
      int arow = wm * 64 + i * 16 + lr;
      int brow = wn * 64 + i * 16 + lr;
      #pragma unroll
      for (int ks = 0; ks < 2; ++ks) {
        int ac = ((ks * 4 + kg) ^ (arow & 7)) * 8;
        int bc = ((ks * 4 + kg) ^ (brow & 7)) * 8;
        ah[i][ks] = *(const bf16x8*)&Ah[arow * 64 + ac];
        al[i][ks] = *(const bf16x8*)&Al[arow * 64 + ac];
        bh[i][ks] = *(const bf16x8*)&Bh[brow * 64 + bc];
        bl[i][ks] = *(const bf16x8*)&Bl[brow * 64 + bc];
      }
    }
    #pragma unroll
    for (int i = 0; i < 4; ++i)
      #pragma unroll
      for (int j = 0; j < 4; ++j)
        #pragma unroll
        for (int ks = 0; ks < 2; ++ks) {
          acc[i][j] = __builtin_amdgcn_mfma_f32_16x16x32_bf16(ah[i][ks], bh[j][ks], acc[i][j], 0, 0, 0);
          acc[i][j] = __builtin_amdgcn_mfma_f32_16x16x32_bf16(al[i][ks], bh[j][ks], acc[i][j], 0, 0, 0);
          acc[i][j] = __builtin_amdgcn_mfma_f32_16x16x32_bf16(ah[i][ks], bl[j][ks], acc[i][j], 0, 0, 0);
        }
  }

  // ---- epilogue: C/D col=lane&15, row=(lane>>4)*4+reg (m89/m91) ----
  float bv[4];
  #pragma unroll
  for (int j = 0; j < 4; ++j) bv[j] = bias[wn * 64 + j * 16 + lr];
  #pragma unroll
  for (int i = 0; i < 4; ++i) {
    #pragma unroll
    for (int j = 0; j < 4; ++j) {
      int col = wn * 64 + j * 16 + lr;
      #pragma unroll
      for (int rg = 0; rg < 4; ++rg) {
        int gm = m0 + wm * 64 + i * 16 + kg * 4 + rg;
        if (gm < N) out[(size_t)gm * 128 + col] = acc[i][j][rg] + bv[j];
      }
    }
  }
}

// ---------------- fallback path (round-1, proven) ----------------

__global__ __launch_bounds__(256, 4)
void gemm_kernel(const float* __restrict__ x, const float* __restrict__ Wself,
                 const float* __restrict__ Wrels, const float* __restrict__ bias,
                 float* __restrict__ out, float* __restrict__ Y, int N, int R) {
  __shared__ float xs[64][68];
  __shared__ float ws[64][68];
  const int m0 = blockIdx.x * 64;
  const int nt = blockIdx.y;
  const float* Wp = (nt < 2) ? (Wself + nt * 64 * 128)
                             : (Wrels + (size_t)(nt - 2) * 64 * 128);
  const int t  = threadIdx.x;
  const int tm = t >> 4;
  const int tn = t & 15;
  float acc[4][4] = {};
  for (int ph = 0; ph < 2; ++ph) {
    __syncthreads();
    #pragma unroll
    for (int i = 0; i < 4; ++i) {
      int L = t + i * 256;
      int row = L >> 4;
      int c4 = L & 15;
      int gm = m0 + row;
      float4 xv = make_float4(0.f, 0.f, 0.f, 0.f);
      if (gm < N) xv = ((const float4*)(x + (size_t)gm * 128 + ph * 64))[c4];
      *((float4*)&xs[row][c4 * 4]) = xv;
      float4 wv = ((const float4*)(Wp + (size_t)row * 128 + ph * 64))[c4];
      *((float4*)&ws[row][c4 * 4]) = wv;
    }
    __syncthreads();
    #pragma unroll
    for (int kk = 0; kk < 16; ++kk) {
      float4 a[4], b[4];
      #pragma unroll
      for (int i = 0; i < 4; ++i) a[i] = *(const float4*)&xs[i * 16 + tm][kk * 4];
      #pragma unroll
      for (int j = 0; j < 4; ++j) b[j] = *(const float4*)&ws[j * 16 + tn][kk * 4];
      #pragma unroll
      for (int i = 0; i < 4; ++i)
        #pragma unroll
        for (int j = 0; j < 4; ++j) {
          acc[i][j] += a[i].x * b[j].x;
          acc[i][j] += a[i].y * b[j].y;
          acc[i][j] += a[i].z * b[j].z;
          acc[i][j] += a[i].w * b[j].w;
        }
    }
  }
  const int YS = R * 128;
  #pragma unroll
  for (int i = 0; i < 4; ++i) {
    int gm = m0 + i * 16 + tm;
    if (gm >= N) continue;
    #pragma unroll
    for (int j = 0; j < 4; ++j) {
      int col = j * 16 + tn;
      float v = acc[i][j];
      if (nt < 2) {
        int oc = nt * 64 + col;
        out[(size_t)gm * 128 + oc] = v + bias[oc];
      } else {
        int q = nt - 2;
        Y[(size_t)gm * YS + q * 64 + col] = v;
      }
    }
  }
}

__global__ __launch_bounds__(256)
void scatter_kernel(const float* __restrict__ Y, const int* __restrict__ src,
                    const int* __restrict__ dst, const float* __restrict__ vals,
                    float* __restrict__ out, long long total_slots, int E, int YS4) {
  long long tid = (long long)blockIdx.x * 256 + threadIdx.x;
  long long slot = tid >> 5;
  int lane = (int)(tid & 31);
  if (slot >= total_slots) return;
  int r = (int)(slot / E);
  int s = src[slot];
  int d = dst[slot];
  float v = vals[slot];
  float4 y = ((const float4*)Y)[(size_t)s * YS4 + r * 32 + lane];
  float* o = out + (size_t)d * 128 + lane * 4;
  atomicAdd(o + 0, v * y.x);
  atomicAdd(o + 1, v * y.y);
  atomicAdd(o + 2, v * y.z);
  atomicAdd(o + 3, v * y.w);
}

// ---------------- launch ----------------

extern "C" void kernel_launch(void* const* d_in, const int* in_sizes, int n_in,
                              void* d_out, int out_size, void* d_ws, size_t ws_size,
                              hipStream_t stream) {
  const float* x     = (const float*)d_in[0];
  const int*   src   = (const int*)d_in[1];
  const int*   dst   = (const int*)d_in[2];
  const float* vals  = (const float*)d_in[3];
  const float* Wself = (const float*)d_in[4];
  const float* bias  = (const float*)d_in[5];
  const float* Wrels = (const float*)d_in[6];
  float*       out   = (float*)d_out;

  const int N = in_sizes[0] / 128;
  const int R = in_sizes[6] / (128 * 128);
  const int E = in_sizes[1] / R;
  const int total = R * E;
  const int keys = R * N;
  const int nb = (keys + 1023) / 1024;

  // workspace layout (fast path)
  size_t aggBytes  = (((size_t)N * R * 128 * sizeof(u16)) + 255) & ~(size_t)255;  // per hi/lo
  size_t curBytes  = ((size_t)keys * sizeof(int) + 255) & ~(size_t)255;
  size_t edgeBytes = ((size_t)total * sizeof(int2) + 255) & ~(size_t)255;
  size_t bsBytes   = ((size_t)nb * sizeof(int) + 255) & ~(size_t)255;
  size_t wBytes    = ((size_t)128 * 512 * sizeof(u16) + 255) & ~(size_t)255;
  size_t need = 2 * aggBytes + curBytes + edgeBytes + bsBytes + 2 * wBytes + 512;

  if (ws_size >= need && R == 3 && nb <= 1024 && (keys % 4) == 0) {
    char* base = (char*)d_ws;
    u16*   Agghi     = (u16*)base;    base += aggBytes;
    u16*   Agglo     = (u16*)base;    base += aggBytes;
    int*   cursor    = (int*)base;    base += curBytes;
    int*   blockSums = (int*)base;    base += bsBytes;
    int2*  edges     = (int2*)base;   base += edgeBytes;
    u16*   Whi       = (u16*)base;    base += wBytes;
    u16*   Wlo       = (u16*)base;

    hipMemsetAsync(cursor, 0, (size_t)keys * sizeof(int), stream);
    hist_kernel<<<(total + 255) / 256, 256, 0, stream>>>(dst, cursor, total, N, E);
    scanA_kernel<<<nb, 256, 0, stream>>>(cursor, blockSums, keys);
    scanB_kernel<<<1, 1024, 0, stream>>>(blockSums, nb);
    scanC_kernel<<<nb, 256, 0, stream>>>(cursor, blockSums, keys);
    fill_kernel<<<(total + 255) / 256, 256, 0, stream>>>(dst, src, vals, cursor, edges, total, N, E);
    split_w_kernel<<<64, 256, 0, stream>>>(Wself, Wrels, Whi, Wlo);
    aggregate_kernel<<<(keys + 3) / 4, 256, 0, stream>>>(x, edges, cursor, Agghi, Agglo, N, keys);
    gemm_mfma<<<(N + 127) / 128, 256, 0, stream>>>(x, Agghi, Agglo, Whi, Wlo, bias, out, N);
  } else {
    // fallback: dense Y + atomic scatter (round-1 path)
    float* Y = (float*)d_ws;
    dim3 g1((N + 63) / 64, 2 + 2 * R);
    gemm_kernel<<<g1, 256, 0, stream>>>(x, Wself, Wrels, bias, out, Y, N, R);
    long long slots = (long long)R * E;
    long long threads = slots * 32;
    int blocks = (int)((threads + 255) / 256);
    scatter_kernel<<<blocks, 256, 0, stream>>>(Y, src, dst, vals, out, slots, E, R * 32);
  }
}